// Round 2
// baseline (1841.467 us; speedup 1.0000x reference)
//
#include <hip/hip_runtime.h>
#include <math.h>

#define NHEADS 8
#define BATCH  256
#define HWTOK  196
#define MTOT   50176         // 1024 windows * 49
#define CHW    128           // windows per chunk (multiple of 4; CHW*49 % 64 == 0)
#define CHROWS (CHW * 49)    // 6272 rows per chunk

// ---------------------------------------------------------------------------
// transpose conv_w (o,c) -> (c,o)
__global__ void k_transpose_w(const float* __restrict__ w, float* __restrict__ wt) {
  int o = blockIdx.x, c = threadIdx.x;
  wt[c * 256 + o] = w[o * 256 + c];
}

__device__ __forceinline__ float gelu_exact(float x) {
  return 0.5f * x * (1.0f + erff(x * 0.70710678118654752f));
}

// window-major global row m -> token-major global row
__device__ __forceinline__ int window_reverse_row(int m) {
  int widx = m / 49, pos = m % 49;
  int b = widx >> 2, wh = (widx >> 1) & 1, ww = widx & 1;
  int i = pos / 7, j = pos % 7;
  return b * 196 + (wh * 7 + i) * 14 + (ww * 7 + j);
}

// ---------------------------------------------------------------------------
// Conv as GEMM reading x K-major: tok[b*196+m][n] = sum_k x[b][k][m] * cwT[k][n] + bias
__global__ __launch_bounds__(256) void k_conv_gemm(const float* __restrict__ x,
                                                   const float* __restrict__ Bw,
                                                   const float* __restrict__ bias,
                                                   float* __restrict__ tok) {
  __shared__ float As[16][68];
  __shared__ float Bs[16][68];
  const int b = blockIdx.z;
  const int m0 = blockIdx.x * 64, n0 = blockIdx.y * 64;
  const int t = threadIdx.x;
  const int tx = t & 15, ty = t >> 4;
  const int kr = t >> 4;          // 0..15
  const int mc = (t & 15) << 2;   // 0..60
  const float* xb = x + (size_t)b * 256 * HWTOK;
  float acc[4][4] = {};
  for (int k0 = 0; k0 < 256; k0 += 16) {
    float4 av = make_float4(0.f, 0.f, 0.f, 0.f);
    if (m0 + mc < HWTOK)  // HWTOK multiple of 4 -> float4-granular guard exact
      av = *(const float4*)(xb + (size_t)(k0 + kr) * HWTOK + m0 + mc);
    float4 bv = *(const float4*)(Bw + (size_t)(k0 + kr) * 256 + n0 + mc);
    __syncthreads();
    *(float4*)&As[kr][mc] = av;
    *(float4*)&Bs[kr][mc] = bv;
    __syncthreads();
#pragma unroll
    for (int kk = 0; kk < 16; ++kk) {
      float a[4], bb[4];
#pragma unroll
      for (int i = 0; i < 4; ++i) a[i] = As[kk][ty * 4 + i];
#pragma unroll
      for (int j = 0; j < 4; ++j) bb[j] = Bs[kk][tx * 4 + j];
#pragma unroll
      for (int i = 0; i < 4; ++i)
#pragma unroll
        for (int j = 0; j < 4; ++j) acc[i][j] = fmaf(a[i], bb[j], acc[i][j]);
    }
  }
#pragma unroll
  for (int i = 0; i < 4; ++i) {
    int m = m0 + ty * 4 + i;
    if (m < HWTOK) {
#pragma unroll
      for (int j = 0; j < 4; ++j) {
        int n = n0 + tx * 4 + j;
        tok[((size_t)b * HWTOK + m) * 256 + n] = acc[i][j] + bias[n];
      }
    }
  }
}

// ---------------------------------------------------------------------------
// Generic fp32 GEMM, 64x64 tile, BK=16. M = grid.x*64 (exact).
// EPI 0: C[m] = acc+bias            (C local)
// EPI 1: C[m] = gelu(acc+bias)      (C local)
// EPI 2: C[wrr(rowbase+m)] = acc+bias + C[wrr(rowbase+m)]   (C global, in-place residual)
// EPI 3: C[rowbase+m] += acc+bias                            (C global, in-place residual)
template <int EPI>
__global__ __launch_bounds__(256) void k_gemm64(const float* __restrict__ A,
                                                const float* __restrict__ B,
                                                const float* __restrict__ bias,
                                                float* __restrict__ Cmat,
                                                int rowbase, int N, int K) {
  __shared__ float As[16][68];
  __shared__ float Bs[16][68];
  const int t = threadIdx.x;
  const int tx = t & 15, ty = t >> 4;
  const int m0 = blockIdx.x * 64, n0 = blockIdx.y * 64;
  const int arow = t >> 2, acol = (t & 3) << 2;
  const int brow = t >> 4, bcol = (t & 15) << 2;
  float acc[4][4] = {};
  for (int k0 = 0; k0 < K; k0 += 16) {
    float4 av = *(const float4*)(A + (size_t)(m0 + arow) * K + k0 + acol);
    float4 bv = *(const float4*)(B + (size_t)(k0 + brow) * N + n0 + bcol);
    __syncthreads();
    As[acol + 0][arow] = av.x;
    As[acol + 1][arow] = av.y;
    As[acol + 2][arow] = av.z;
    As[acol + 3][arow] = av.w;
    *(float4*)&Bs[brow][bcol] = bv;
    __syncthreads();
#pragma unroll
    for (int kk = 0; kk < 16; ++kk) {
      float a[4], bb[4];
#pragma unroll
      for (int i = 0; i < 4; ++i) a[i] = As[kk][ty * 4 + i];
#pragma unroll
      for (int j = 0; j < 4; ++j) bb[j] = Bs[kk][tx * 4 + j];
#pragma unroll
      for (int i = 0; i < 4; ++i)
#pragma unroll
        for (int j = 0; j < 4; ++j) acc[i][j] = fmaf(a[i], bb[j], acc[i][j]);
    }
  }
#pragma unroll
  for (int i = 0; i < 4; ++i) {
    int m = m0 + ty * 4 + i;
    int row;
    if (EPI == 2) row = window_reverse_row(rowbase + m);
    else if (EPI == 3) row = rowbase + m;
    else row = m;
#pragma unroll
    for (int j = 0; j < 4; ++j) {
      int n = n0 + tx * 4 + j;
      float v = acc[i][j] + bias[n];
      if (EPI == 1) v = gelu_exact(v);
      if (EPI == 2 || EPI == 3) v += Cmat[(size_t)row * N + n];
      Cmat[(size_t)row * N + n] = v;
    }
  }
}

// ---------------------------------------------------------------------------
// LayerNorm over C=256, one wave per token, chunk of CHROWS tokens starting at
// global token row `rowbase`. Output is chunk-local rows; WINDOW applies the
// window partition permutation (window-major global row - rowbase).
template <bool WINDOW>
__global__ __launch_bounds__(256) void k_layernorm(const float* __restrict__ in,
                                                   const float* __restrict__ g,
                                                   const float* __restrict__ bta,
                                                   float* __restrict__ out,
                                                   int rowbase) {
  int wid = threadIdx.x >> 6, lane = threadIdx.x & 63;
  int li = blockIdx.x * 4 + wid;          // chunk-local token index
  int token = rowbase + li;               // global token row
  const float4 xv = *(const float4*)(in + (size_t)token * 256 + lane * 4);
  float s = xv.x + xv.y + xv.z + xv.w;
  float sq = xv.x * xv.x + xv.y * xv.y + xv.z * xv.z + xv.w * xv.w;
#pragma unroll
  for (int off = 32; off >= 1; off >>= 1) {
    s += __shfl_xor(s, off);
    sq += __shfl_xor(sq, off);
  }
  float mean = s * (1.f / 256.f);
  float var = sq * (1.f / 256.f) - mean * mean;
  float rstd = rsqrtf(var + 1e-5f);
  float4 gv = *(const float4*)(g + lane * 4);
  float4 bv = *(const float4*)(bta + lane * 4);
  float4 ov;
  ov.x = (xv.x - mean) * rstd * gv.x + bv.x;
  ov.y = (xv.y - mean) * rstd * gv.y + bv.y;
  ov.z = (xv.z - mean) * rstd * gv.z + bv.z;
  ov.w = (xv.w - mean) * rstd * gv.w + bv.w;
  int orow;
  if (WINDOW) {
    int b = token / 196, hw = token % 196;
    int h14 = hw / 14, w14 = hw % 14;
    int wh = h14 / 7, i = h14 % 7, ww = w14 / 7, j = w14 % 7;
    int widx = (b * 2 + wh) * 2 + ww;
    orow = widx * 49 + i * 7 + j - rowbase;  // chunk-local window-major row
  } else {
    orow = li;
  }
  *(float4*)(out + (size_t)orow * 256 + lane * 4) = ov;
}

// ---------------------------------------------------------------------------
// Attention on one chunk: block = (local window, head). qkv/o are chunk-local.
__global__ __launch_bounds__(256) void k_attention(const float* __restrict__ qkv,
                                                   const float* __restrict__ rpb,
                                                   float* __restrict__ o) {
  const int lw = blockIdx.x >> 3;
  const int head = blockIdx.x & 7;
  __shared__ float q[49][33], ksm[49][33], vsm[49][33];
  __shared__ float attn[49][49];
  const int t = threadIdx.x;
  const size_t base = (size_t)lw * 49 * 768 + head * 32;
  for (int e = t; e < 49 * 32; e += 256) {
    int n = e >> 5, d = e & 31;
    size_t rb = base + (size_t)n * 768 + d;
    q[n][d] = qkv[rb];
    ksm[n][d] = qkv[rb + 256];
    vsm[n][d] = qkv[rb + 512];
  }
  __syncthreads();
  const float scale = 0.17677669529663687f; // 1/sqrt(32)
  for (int e = t; e < 49 * 49; e += 256) {
    int i = e / 49, j = e % 49;
    float s = 0.f;
#pragma unroll
    for (int d = 0; d < 32; ++d) s = fmaf(q[i][d], ksm[j][d], s);
    int qi = i / 7, qj = i % 7, ki = j / 7, kj = j % 7;
    int rel = (qi - ki + 6) * 13 + (qj - kj + 6);
    attn[i][j] = s * scale + rpb[rel * 8 + head];
  }
  __syncthreads();
  int wid = t >> 6, lane = t & 63;
  for (int row = wid; row < 49; row += 4) {
    float val = (lane < 49) ? attn[row][lane] : -INFINITY;
    float mx = val;
#pragma unroll
    for (int off = 32; off >= 1; off >>= 1) mx = fmaxf(mx, __shfl_xor(mx, off));
    float p = __expf(val - mx);
    if (lane >= 49) p = 0.f;
    float sum = p;
#pragma unroll
    for (int off = 32; off >= 1; off >>= 1) sum += __shfl_xor(sum, off);
    if (lane < 49) attn[row][lane] = p / sum;
  }
  __syncthreads();
  for (int e = t; e < 49 * 32; e += 256) {
    int i = e >> 5, d = e & 31;
    float s = 0.f;
#pragma unroll
    for (int j = 0; j < 49; ++j) s = fmaf(attn[i][j], vsm[j][d], s);
    o[((size_t)lw * 49 + i) * 256 + head * 32 + d] = s;
  }
}

// ---------------------------------------------------------------------------
__global__ __launch_bounds__(256) void k_pool(const float* __restrict__ tok,
                                              float* __restrict__ pooled) {
  int b = blockIdx.x, c = threadIdx.x;
  float s = 0.f;
  for (int hw = 0; hw < 196; ++hw) s += tok[((size_t)b * 196 + hw) * 256 + c];
  pooled[b * 256 + c] = s * (1.f / 196.f);
}

__global__ __launch_bounds__(64) void k_head(const float* __restrict__ pooled,
                                             const float* __restrict__ w,
                                             const float* __restrict__ bias,
                                             float* __restrict__ out) {
  int b = blockIdx.x, t = threadIdx.x;
  if (t < 7) {
    float s = bias[t];
    for (int c = 0; c < 256; ++c) s = fmaf(pooled[b * 256 + c], w[c * 7 + t], s);
    out[b * 7 + t] = s;
  }
}

// ---------------------------------------------------------------------------
extern "C" void kernel_launch(void* const* d_in, const int* in_sizes, int n_in,
                              void* d_out, int out_size, void* d_ws, size_t ws_size,
                              hipStream_t stream) {
  const float* x      = (const float*)d_in[0];
  const float* conv_w = (const float*)d_in[1];
  const float* conv_b = (const float*)d_in[2];
  const float* ln1_g  = (const float*)d_in[3];
  const float* ln1_b  = (const float*)d_in[4];
  const float* qkv_w  = (const float*)d_in[5];
  const float* qkv_b  = (const float*)d_in[6];
  const float* rpb    = (const float*)d_in[7];
  const float* proj_w = (const float*)d_in[8];
  const float* proj_b = (const float*)d_in[9];
  const float* ln2_g  = (const float*)d_in[10];
  const float* ln2_b  = (const float*)d_in[11];
  const float* fc1_w  = (const float*)d_in[12];
  const float* fc1_b  = (const float*)d_in[13];
  const float* fc2_w  = (const float*)d_in[14];
  const float* fc2_b  = (const float*)d_in[15];
  const float* fco_w  = (const float*)d_in[16];
  const float* fco_b  = (const float*)d_in[17];
  float* out = (float*)d_out;
  float* ws = (float*)d_ws;

  // workspace layout (floats); total = 22,609,920 floats = 90.4 MB
  float* tok  = ws;                        // 12,845,056 : running residual (token-major)
  float* Abuf = tok + 12845056;            //  1,605,632 : LN out chunk (CHROWS x 256)
  float* Bbuf = Abuf + 1605632;            //  6,422,528 : qkv chunk (x768) / h1 chunk (x1024)
  float* Cbuf = Bbuf + 6422528;            //  1,605,632 : attn out chunk (CHROWS x 256)
  float* cwT  = Cbuf + 1605632;            //     65,536
  float* pool = cwT + 65536;               //     65,536

  k_transpose_w<<<256, 256, 0, stream>>>(conv_w, cwT);
  k_conv_gemm<<<dim3(4, 4, BATCH), 256, 0, stream>>>(x, cwT, conv_b, tok);

  for (int c = 0; c < 1024 / CHW; ++c) {
    const int rowbase = c * CHROWS;
    // LN1 + window partition -> Abuf (chunk-local window-major)
    k_layernorm<true><<<CHROWS / 4, 256, 0, stream>>>(tok, ln1_g, ln1_b, Abuf, rowbase);
    // qkv = Abuf @ qkv_w + qkv_b -> Bbuf
    k_gemm64<0><<<dim3(CHROWS / 64, 12), 256, 0, stream>>>(Abuf, qkv_w, qkv_b, Bbuf, 0, 768, 256);
    // attention -> Cbuf
    k_attention<<<CHW * 8, 256, 0, stream>>>(Bbuf, rpb, Cbuf);
    // proj + residual (window reverse, in-place on tok)
    k_gemm64<2><<<dim3(CHROWS / 64, 4), 256, 0, stream>>>(Cbuf, proj_w, proj_b, tok, rowbase, 256, 256);
    // LN2 -> Abuf (chunk-local token-major)
    k_layernorm<false><<<CHROWS / 4, 256, 0, stream>>>(tok, ln2_g, ln2_b, Abuf, rowbase);
    // h1 = gelu(Abuf @ fc1_w + fc1_b) -> Bbuf
    k_gemm64<1><<<dim3(CHROWS / 64, 16), 256, 0, stream>>>(Abuf, fc1_w, fc1_b, Bbuf, 0, 1024, 256);
    // tok[rowbase+m] += Bbuf @ fc2_w + fc2_b
    k_gemm64<3><<<dim3(CHROWS / 64, 4), 256, 0, stream>>>(Bbuf, fc2_w, fc2_b, tok, rowbase, 256, 1024);
  }

  k_pool<<<BATCH, 256, 0, stream>>>(tok, pool);
  k_head<<<BATCH, 64, 0, stream>>>(pool, fco_w, fco_b, out);
}

// Round 3
// 711.285 us; speedup vs baseline: 2.5889x; 2.5889x over previous
//
#include <hip/hip_runtime.h>
#include <math.h>

#define NHEADS 8
#define BATCH  256
#define HWTOK  196
#define MTOT   50176          // 1024 windows * 49
#define CHW    256            // windows per chunk
#define CHROWS (CHW * 49)     // 12544 rows per chunk (= 98 * 128)

#define BM 128
#define BN 128
#define BK 64

typedef short bfrag8 __attribute__((ext_vector_type(8)));
typedef float ffrag4 __attribute__((ext_vector_type(4)));

// ---------------------------------------------------------------------------
__device__ __forceinline__ unsigned short f2bf(float f) {
  union { float f; unsigned u; } v; v.f = f;
  unsigned r = v.u + 0x7fffu + ((v.u >> 16) & 1u);   // RNE
  return (unsigned short)(r >> 16);
}
__device__ __forceinline__ float bf2f(unsigned short b) {
  union { unsigned u; float f; } v; v.u = ((unsigned)b) << 16;
  return v.f;
}
__device__ __forceinline__ float gelu_exact(float x) {
  return 0.5f * x * (1.0f + erff(x * 0.70710678118654752f));
}
// window-major global row m -> token-major global row
__device__ __forceinline__ int window_reverse_row(int m) {
  int widx = m / 49, pos = m % 49;
  int b = widx >> 2, wh = (widx >> 1) & 1, ww = widx & 1;
  int i = pos / 7, j = pos % 7;
  return b * 196 + (wh * 7 + i) * 14 + (ww * 7 + j);
}

__device__ __forceinline__ void gload16(const void* g, void* l) {
  __builtin_amdgcn_global_load_lds(
      (const __attribute__((address_space(1))) void*)g,
      (__attribute__((address_space(3))) void*)l, 16, 0, 0);
}

// ---------------------------------------------------------------------------
// bf16 MFMA GEMM: A [M][K] bf16, BT [N][K] bf16, 128x128 tile, BK=64.
// EPI 0: Cout(bf16)[m][n] = acc+bias
// EPI 1: Cout(bf16)[m][n] = gelu(acc+bias)
// EPI 2: Cout(f32)[wrr(rowbase+m)][n] += acc+bias   (residual RMW)
// EPI 3: Cout(f32)[rowbase+m][n]      += acc+bias   (residual RMW)
// EPI 4: Cout(f32)[m][n]               = acc+bias
template <int EPI>
__global__ __launch_bounds__(256) void k_gemm_mfma(const unsigned short* __restrict__ A,
                                                   const unsigned short* __restrict__ BT,
                                                   const float* __restrict__ bias,
                                                   void* __restrict__ Cout,
                                                   int rowbase, int N, int K) {
  __shared__ __align__(128) unsigned short As[BM * BK];
  __shared__ __align__(128) unsigned short Bs[BN * BK];
  const int t = threadIdx.x;
  const int lane = t & 63, w = t >> 6;
  const int wr = w >> 1, wc = w & 1;
  const int m0 = blockIdx.x * BM, n0 = blockIdx.y * BN;
  const int rA = lane >> 3;            // 0..7 (row within 8-row segment)
  const int kin = (lane & 7) * 8;      // element offset along K
  ffrag4 acc[4][4] = {};

  for (int k0 = 0; k0 < K; k0 += BK) {
#pragma unroll
    for (int i = 0; i < 4; ++i) {
      const int seg = i * 4 + w;       // 0..15, wave-uniform
      const int row = seg * 8 + rA;    // 0..127
      gload16(A + (size_t)(m0 + row) * K + k0 + kin, (char*)As + seg * 1024);
      gload16(BT + (size_t)(n0 + row) * K + k0 + kin, (char*)Bs + seg * 1024);
    }
    __syncthreads();                    // drains vmcnt before barrier
#pragma unroll
    for (int kk = 0; kk < BK; kk += 32) {
      bfrag8 af[4], bfr[4];
#pragma unroll
      for (int mi = 0; mi < 4; ++mi) {
        int row = wr * 64 + mi * 16 + (lane & 15);
        af[mi] = *(const bfrag8*)&As[row * BK + kk + (lane >> 4) * 8];
      }
#pragma unroll
      for (int ni = 0; ni < 4; ++ni) {
        int col = wc * 64 + ni * 16 + (lane & 15);
        bfr[ni] = *(const bfrag8*)&Bs[col * BK + kk + (lane >> 4) * 8];
      }
#pragma unroll
      for (int mi = 0; mi < 4; ++mi)
#pragma unroll
        for (int ni = 0; ni < 4; ++ni)
          acc[mi][ni] = __builtin_amdgcn_mfma_f32_16x16x32_bf16(af[mi], bfr[ni], acc[mi][ni], 0, 0, 0);
    }
    __syncthreads();
  }

  const int cr = (lane >> 4) * 4;      // C row base within 16
  const int cc = lane & 15;            // C col within 16
#pragma unroll
  for (int mi = 0; mi < 4; ++mi) {
#pragma unroll
    for (int j = 0; j < 4; ++j) {
      const int m = m0 + wr * 64 + mi * 16 + cr + j;
      int row;
      if (EPI == 2) row = window_reverse_row(rowbase + m);
      else if (EPI == 3) row = rowbase + m;
      else row = m;
#pragma unroll
      for (int ni = 0; ni < 4; ++ni) {
        const int n = n0 + wc * 64 + ni * 16 + cc;
        float v = acc[mi][ni][j] + bias[n];
        if (EPI == 1) v = gelu_exact(v);
        if (EPI == 0 || EPI == 1) {
          ((unsigned short*)Cout)[(size_t)m * N + n] = f2bf(v);
        } else if (EPI == 4) {
          ((float*)Cout)[(size_t)row * N + n] = v;
        } else {
          float* p = (float*)Cout + (size_t)row * N + n;
          *p += v;
        }
      }
    }
  }
}

// ---------------------------------------------------------------------------
// weight transpose-cast: w (K,N) f32 -> wt [N][K] bf16
__global__ __launch_bounds__(256) void k_wtrans(const float* __restrict__ w,
                                                unsigned short* __restrict__ wt,
                                                int K, int N) {
  __shared__ float tile[32][33];
  int k0 = blockIdx.x * 32, n0 = blockIdx.y * 32;
  int tx = threadIdx.x & 31, ty = threadIdx.x >> 5;
#pragma unroll
  for (int r = 0; r < 4; ++r)
    tile[ty + r * 8][tx] = w[(size_t)(k0 + ty + r * 8) * N + n0 + tx];
  __syncthreads();
#pragma unroll
  for (int r = 0; r < 4; ++r)
    wt[(size_t)(n0 + ty + r * 8) * K + k0 + tx] = f2bf(tile[tx][ty + r * 8]);
}

// cast conv_w (o,c) f32 -> bf16 (already [N][K])
__global__ __launch_bounds__(256) void k_cast(const float* __restrict__ w,
                                              unsigned short* __restrict__ wb, int n) {
  int i = blockIdx.x * 256 + threadIdx.x;
  if (i < n) wb[i] = f2bf(w[i]);
}

// transpose x: (B, C=256, HW=196) f32 -> xt (B*HW, C) bf16
__global__ __launch_bounds__(256) void k_transpose_x(const float* __restrict__ x,
                                                     unsigned short* __restrict__ xt) {
  __shared__ float tile[32][33];
  int b = blockIdx.x;
  int hw0 = blockIdx.y * 32;
  int c0 = blockIdx.z * 32;
  int tx = threadIdx.x & 31, ty = threadIdx.x >> 5;
#pragma unroll
  for (int r = 0; r < 4; ++r) {
    int c = c0 + ty + r * 8, hw = hw0 + tx;
    if (hw < HWTOK) tile[ty + r * 8][tx] = x[((size_t)b * 256 + c) * HWTOK + hw];
  }
  __syncthreads();
#pragma unroll
  for (int r = 0; r < 4; ++r) {
    int hw = hw0 + ty + r * 8, c = c0 + tx;
    if (hw < HWTOK) xt[((size_t)b * HWTOK + hw) * 256 + c] = f2bf(tile[tx][ty + r * 8]);
  }
}

// ---------------------------------------------------------------------------
// LayerNorm over C=256, one wave/token, fp32 in -> bf16 out (chunk-local rows).
template <bool WINDOW>
__global__ __launch_bounds__(256) void k_layernorm(const float* __restrict__ in,
                                                   const float* __restrict__ g,
                                                   const float* __restrict__ bta,
                                                   unsigned short* __restrict__ out,
                                                   int rowbase) {
  int wid = threadIdx.x >> 6, lane = threadIdx.x & 63;
  int li = blockIdx.x * 4 + wid;
  int token = rowbase + li;
  const float4 xv = *(const float4*)(in + (size_t)token * 256 + lane * 4);
  float s = xv.x + xv.y + xv.z + xv.w;
  float sq = xv.x * xv.x + xv.y * xv.y + xv.z * xv.z + xv.w * xv.w;
#pragma unroll
  for (int off = 32; off >= 1; off >>= 1) {
    s += __shfl_xor(s, off);
    sq += __shfl_xor(sq, off);
  }
  float mean = s * (1.f / 256.f);
  float var = sq * (1.f / 256.f) - mean * mean;
  float rstd = rsqrtf(var + 1e-5f);
  float4 gv = *(const float4*)(g + lane * 4);
  float4 bv = *(const float4*)(bta + lane * 4);
  ushort4 ov;
  ov.x = f2bf((xv.x - mean) * rstd * gv.x + bv.x);
  ov.y = f2bf((xv.y - mean) * rstd * gv.y + bv.y);
  ov.z = f2bf((xv.z - mean) * rstd * gv.z + bv.z);
  ov.w = f2bf((xv.w - mean) * rstd * gv.w + bv.w);
  int orow;
  if (WINDOW) {
    int b = token / 196, hw = token % 196;
    int h14 = hw / 14, w14 = hw % 14;
    int wh = h14 / 7, i = h14 % 7, ww = w14 / 7, j = w14 % 7;
    int widx = (b * 2 + wh) * 2 + ww;
    orow = widx * 49 + i * 7 + j - rowbase;
  } else {
    orow = li;
  }
  *(ushort4*)(out + (size_t)orow * 256 + lane * 4) = ov;
}

// ---------------------------------------------------------------------------
// Attention on a chunk: block = (local window, head); bf16 qkv in, bf16 o out.
__global__ __launch_bounds__(256) void k_attention(const unsigned short* __restrict__ qkv,
                                                   const float* __restrict__ rpb,
                                                   unsigned short* __restrict__ o) {
  const int lw = blockIdx.x >> 3;
  const int head = blockIdx.x & 7;
  __shared__ float q[49][33], ksm[49][33], vsm[49][33];
  __shared__ float attn[49][49];
  const int t = threadIdx.x;
  const size_t base = (size_t)lw * 49 * 768 + head * 32;
  for (int e = t; e < 49 * 32; e += 256) {
    int n = e >> 5, d = e & 31;
    size_t rb = base + (size_t)n * 768 + d;
    q[n][d] = bf2f(qkv[rb]);
    ksm[n][d] = bf2f(qkv[rb + 256]);
    vsm[n][d] = bf2f(qkv[rb + 512]);
  }
  __syncthreads();
  const float scale = 0.17677669529663687f; // 1/sqrt(32)
  for (int e = t; e < 49 * 49; e += 256) {
    int i = e / 49, j = e % 49;
    float s = 0.f;
#pragma unroll
    for (int d = 0; d < 32; ++d) s = fmaf(q[i][d], ksm[j][d], s);
    int qi = i / 7, qj = i % 7, ki = j / 7, kj = j % 7;
    int rel = (qi - ki + 6) * 13 + (qj - kj + 6);
    attn[i][j] = s * scale + rpb[rel * 8 + head];
  }
  __syncthreads();
  int wid = t >> 6, lane = t & 63;
  for (int row = wid; row < 49; row += 4) {
    float val = (lane < 49) ? attn[row][lane] : -INFINITY;
    float mx = val;
#pragma unroll
    for (int off = 32; off >= 1; off >>= 1) mx = fmaxf(mx, __shfl_xor(mx, off));
    float p = __expf(val - mx);
    if (lane >= 49) p = 0.f;
    float sum = p;
#pragma unroll
    for (int off = 32; off >= 1; off >>= 1) sum += __shfl_xor(sum, off);
    if (lane < 49) attn[row][lane] = p / sum;
  }
  __syncthreads();
  for (int e = t; e < 49 * 32; e += 256) {
    int i = e >> 5, d = e & 31;
    float s = 0.f;
#pragma unroll
    for (int j = 0; j < 49; ++j) s = fmaf(attn[i][j], vsm[j][d], s);
    o[((size_t)lw * 49 + i) * 256 + head * 32 + d] = f2bf(s);
  }
}

// ---------------------------------------------------------------------------
__global__ __launch_bounds__(256) void k_pool(const float* __restrict__ tok,
                                              float* __restrict__ pooled) {
  int b = blockIdx.x, c = threadIdx.x;
  float s = 0.f;
  for (int hw = 0; hw < 196; ++hw) s += tok[((size_t)b * 196 + hw) * 256 + c];
  pooled[b * 256 + c] = s * (1.f / 196.f);
}

__global__ __launch_bounds__(64) void k_head(const float* __restrict__ pooled,
                                             const float* __restrict__ w,
                                             const float* __restrict__ bias,
                                             float* __restrict__ out) {
  int b = blockIdx.x, t = threadIdx.x;
  if (t < 7) {
    float s = bias[t];
    for (int c = 0; c < 256; ++c) s = fmaf(pooled[b * 256 + c], w[c * 7 + t], s);
    out[b * 7 + t] = s;
  }
}

// ---------------------------------------------------------------------------
extern "C" void kernel_launch(void* const* d_in, const int* in_sizes, int n_in,
                              void* d_out, int out_size, void* d_ws, size_t ws_size,
                              hipStream_t stream) {
  const float* x      = (const float*)d_in[0];
  const float* conv_w = (const float*)d_in[1];
  const float* conv_b = (const float*)d_in[2];
  const float* ln1_g  = (const float*)d_in[3];
  const float* ln1_b  = (const float*)d_in[4];
  const float* qkv_w  = (const float*)d_in[5];
  const float* qkv_b  = (const float*)d_in[6];
  const float* rpb    = (const float*)d_in[7];
  const float* proj_w = (const float*)d_in[8];
  const float* proj_b = (const float*)d_in[9];
  const float* ln2_g  = (const float*)d_in[10];
  const float* ln2_b  = (const float*)d_in[11];
  const float* fc1_w  = (const float*)d_in[12];
  const float* fc1_b  = (const float*)d_in[13];
  const float* fc2_w  = (const float*)d_in[14];
  const float* fc2_b  = (const float*)d_in[15];
  const float* fco_w  = (const float*)d_in[16];
  const float* fco_b  = (const float*)d_in[17];
  float* out = (float*)d_out;
  char* p = (char*)d_ws;

  // workspace layout (bytes), ~92 MB total
  float* tok = (float*)p;                 p += (size_t)MTOT * 256 * 4;        // 51.4 MB
  unsigned short* Bbuf = (unsigned short*)p; p += (size_t)CHROWS * 1024 * 2;  // 25.7 MB (aliases xt)
  unsigned short* Abuf = (unsigned short*)p; p += (size_t)CHROWS * 256 * 2;   // 6.4 MB
  unsigned short* Cbuf = (unsigned short*)p; p += (size_t)CHROWS * 256 * 2;   // 6.4 MB
  unsigned short* cwB  = (unsigned short*)p; p += 65536 * 2;
  unsigned short* qkvT = (unsigned short*)p; p += 196608 * 2;
  unsigned short* projT= (unsigned short*)p; p += 65536 * 2;
  unsigned short* fc1T = (unsigned short*)p; p += 262144 * 2;
  unsigned short* fc2T = (unsigned short*)p; p += 262144 * 2;
  float* pool = (float*)p;                p += 65536 * 4;
  unsigned short* xt = Bbuf;  // x^T lives only before the chunk loop

  // weight prep
  k_cast<<<256, 256, 0, stream>>>(conv_w, cwB, 65536);
  k_wtrans<<<dim3(8, 24), 256, 0, stream>>>(qkv_w, qkvT, 256, 768);
  k_wtrans<<<dim3(8, 8), 256, 0, stream>>>(proj_w, projT, 256, 256);
  k_wtrans<<<dim3(8, 32), 256, 0, stream>>>(fc1_w, fc1T, 256, 1024);
  k_wtrans<<<dim3(32, 8), 256, 0, stream>>>(fc2_w, fc2T, 1024, 256);

  // x^T (bf16) and conv GEMM -> tok (f32, token-major)
  k_transpose_x<<<dim3(BATCH, 7, 8), 256, 0, stream>>>(x, xt);
  k_gemm_mfma<4><<<dim3(MTOT / BM, 256 / BN), 256, 0, stream>>>(xt, cwB, conv_b, tok, 0, 256, 256);

  for (int c = 0; c < 1024 / CHW; ++c) {
    const int rowbase = c * CHROWS;
    // LN1 + window partition -> Abuf (bf16, chunk-local window-major)
    k_layernorm<true><<<CHROWS / 4, 256, 0, stream>>>(tok, ln1_g, ln1_b, Abuf, rowbase);
    // qkv -> Bbuf (bf16)
    k_gemm_mfma<0><<<dim3(CHROWS / BM, 768 / BN), 256, 0, stream>>>(Abuf, qkvT, qkv_b, Bbuf, 0, 768, 256);
    // attention -> Cbuf (bf16)
    k_attention<<<CHW * 8, 256, 0, stream>>>(Bbuf, rpb, Cbuf);
    // proj + residual (window reverse) into tok (f32)
    k_gemm_mfma<2><<<dim3(CHROWS / BM, 256 / BN), 256, 0, stream>>>(Cbuf, projT, proj_b, tok, rowbase, 256, 256);
    // LN2 -> Abuf (bf16, token-major chunk-local)
    k_layernorm<false><<<CHROWS / 4, 256, 0, stream>>>(tok, ln2_g, ln2_b, Abuf, rowbase);
    // h1 = gelu(...) -> Bbuf (bf16)
    k_gemm_mfma<1><<<dim3(CHROWS / BM, 1024 / BN), 256, 0, stream>>>(Abuf, fc1T, fc1_b, Bbuf, 0, 1024, 256);
    // tok += h1 @ fc2
    k_gemm_mfma<3><<<dim3(CHROWS / BM, 256 / BN), 256, 0, stream>>>(Bbuf, fc2T, fc2_b, tok, rowbase, 256, 1024);
  }

  k_pool<<<BATCH, 256, 0, stream>>>(tok, pool);
  k_head<<<BATCH, 64, 0, stream>>>(pool, fco_w, fco_b, out);
}

// Round 4
// 558.739 us; speedup vs baseline: 3.2958x; 1.2730x over previous
//
#include <hip/hip_runtime.h>
#include <math.h>

#define NHEADS 8
#define BATCH  256
#define HWTOK  196
#define MTOT   50176          // 1024 windows * 49
#define CHW    256            // windows per chunk
#define CHROWS (CHW * 49)     // 12544 rows per chunk (= 98 * 128)

#define BM 128
#define BN 128
#define BK 64

typedef short bfrag8 __attribute__((ext_vector_type(8)));
typedef float ffrag4 __attribute__((ext_vector_type(4)));

// ---------------------------------------------------------------------------
__device__ __forceinline__ unsigned short f2bf(float f) {
  union { float f; unsigned u; } v; v.f = f;
  unsigned r = v.u + 0x7fffu + ((v.u >> 16) & 1u);   // RNE
  return (unsigned short)(r >> 16);
}
__device__ __forceinline__ float bf2f(unsigned short b) {
  union { unsigned u; float f; } v; v.u = ((unsigned)b) << 16;
  return v.f;
}
__device__ __forceinline__ float gelu_exact(float x) {
  return 0.5f * x * (1.0f + erff(x * 0.70710678118654752f));
}
// window-major global row m -> token-major global row
__device__ __forceinline__ int window_reverse_row(int m) {
  int widx = m / 49, pos = m % 49;
  int b = widx >> 2, wh = (widx >> 1) & 1, ww = widx & 1;
  int i = pos / 7, j = pos % 7;
  return b * 196 + (wh * 7 + i) * 14 + (ww * 7 + j);
}

__device__ __forceinline__ void gload16(const void* g, void* l) {
  __builtin_amdgcn_global_load_lds(
      (const __attribute__((address_space(1))) void*)g,
      (__attribute__((address_space(3))) void*)l, 16, 0, 0);
}

// ---------------------------------------------------------------------------
// bf16 MFMA GEMM: A [M][K] bf16, BT [N][K] bf16, 128x128 tile, BK=64.
template <int EPI>
__global__ __launch_bounds__(256) void k_gemm_mfma(const unsigned short* __restrict__ A,
                                                   const unsigned short* __restrict__ BT,
                                                   const float* __restrict__ bias,
                                                   void* __restrict__ Cout,
                                                   int rowbase, int N, int K) {
  __shared__ __align__(128) unsigned short As[BM * BK];
  __shared__ __align__(128) unsigned short Bs[BN * BK];
  const int t = threadIdx.x;
  const int lane = t & 63, w = t >> 6;
  const int wr = w >> 1, wc = w & 1;
  const int m0 = blockIdx.x * BM, n0 = blockIdx.y * BN;
  const int rA = lane >> 3;            // 0..7
  const int kin = (lane & 7) * 8;      // element offset along K
  ffrag4 acc[4][4] = {};

  for (int k0 = 0; k0 < K; k0 += BK) {
#pragma unroll
    for (int i = 0; i < 4; ++i) {
      const int seg = i * 4 + w;
      const int row = seg * 8 + rA;
      gload16(A + (size_t)(m0 + row) * K + k0 + kin, (char*)As + seg * 1024);
      gload16(BT + (size_t)(n0 + row) * K + k0 + kin, (char*)Bs + seg * 1024);
    }
    __syncthreads();
#pragma unroll
    for (int kk = 0; kk < BK; kk += 32) {
      bfrag8 af[4], bfr[4];
#pragma unroll
      for (int mi = 0; mi < 4; ++mi) {
        int row = wr * 64 + mi * 16 + (lane & 15);
        af[mi] = *(const bfrag8*)&As[row * BK + kk + (lane >> 4) * 8];
      }
#pragma unroll
      for (int ni = 0; ni < 4; ++ni) {
        int col = wc * 64 + ni * 16 + (lane & 15);
        bfr[ni] = *(const bfrag8*)&Bs[col * BK + kk + (lane >> 4) * 8];
      }
#pragma unroll
      for (int mi = 0; mi < 4; ++mi)
#pragma unroll
        for (int ni = 0; ni < 4; ++ni)
          acc[mi][ni] = __builtin_amdgcn_mfma_f32_16x16x32_bf16(af[mi], bfr[ni], acc[mi][ni], 0, 0, 0);
    }
    __syncthreads();
  }

  const int cr = (lane >> 4) * 4;
  const int cc = lane & 15;
#pragma unroll
  for (int mi = 0; mi < 4; ++mi) {
#pragma unroll
    for (int j = 0; j < 4; ++j) {
      const int m = m0 + wr * 64 + mi * 16 + cr + j;
      int row;
      if (EPI == 2) row = window_reverse_row(rowbase + m);
      else if (EPI == 3) row = rowbase + m;
      else row = m;
#pragma unroll
      for (int ni = 0; ni < 4; ++ni) {
        const int n = n0 + wc * 64 + ni * 16 + cc;
        float v = acc[mi][ni][j] + bias[n];
        if (EPI == 1) v = gelu_exact(v);
        if (EPI == 0 || EPI == 1) {
          ((unsigned short*)Cout)[(size_t)m * N + n] = f2bf(v);
        } else if (EPI == 4) {
          ((float*)Cout)[(size_t)row * N + n] = v;
        } else {
          float* p = (float*)Cout + (size_t)row * N + n;
          *p += v;
        }
      }
    }
  }
}

// ---------------------------------------------------------------------------
__global__ __launch_bounds__(256) void k_wtrans(const float* __restrict__ w,
                                                unsigned short* __restrict__ wt,
                                                int K, int N) {
  __shared__ float tile[32][33];
  int k0 = blockIdx.x * 32, n0 = blockIdx.y * 32;
  int tx = threadIdx.x & 31, ty = threadIdx.x >> 5;
#pragma unroll
  for (int r = 0; r < 4; ++r)
    tile[ty + r * 8][tx] = w[(size_t)(k0 + ty + r * 8) * N + n0 + tx];
  __syncthreads();
#pragma unroll
  for (int r = 0; r < 4; ++r)
    wt[(size_t)(n0 + ty + r * 8) * K + k0 + tx] = f2bf(tile[tx][ty + r * 8]);
}

__global__ __launch_bounds__(256) void k_cast(const float* __restrict__ w,
                                              unsigned short* __restrict__ wb, int n) {
  int i = blockIdx.x * 256 + threadIdx.x;
  if (i < n) wb[i] = f2bf(w[i]);
}

__global__ __launch_bounds__(256) void k_transpose_x(const float* __restrict__ x,
                                                     unsigned short* __restrict__ xt) {
  __shared__ float tile[32][33];
  int b = blockIdx.x;
  int hw0 = blockIdx.y * 32;
  int c0 = blockIdx.z * 32;
  int tx = threadIdx.x & 31, ty = threadIdx.x >> 5;
#pragma unroll
  for (int r = 0; r < 4; ++r) {
    int c = c0 + ty + r * 8, hw = hw0 + tx;
    if (hw < HWTOK) tile[ty + r * 8][tx] = x[((size_t)b * 256 + c) * HWTOK + hw];
  }
  __syncthreads();
#pragma unroll
  for (int r = 0; r < 4; ++r) {
    int hw = hw0 + ty + r * 8, c = c0 + tx;
    if (hw < HWTOK) xt[((size_t)b * HWTOK + hw) * 256 + c] = f2bf(tile[tx][ty + r * 8]);
  }
}

// ---------------------------------------------------------------------------
template <bool WINDOW>
__global__ __launch_bounds__(256) void k_layernorm(const float* __restrict__ in,
                                                   const float* __restrict__ g,
                                                   const float* __restrict__ bta,
                                                   unsigned short* __restrict__ out,
                                                   int rowbase) {
  int wid = threadIdx.x >> 6, lane = threadIdx.x & 63;
  int li = blockIdx.x * 4 + wid;
  int token = rowbase + li;
  const float4 xv = *(const float4*)(in + (size_t)token * 256 + lane * 4);
  float s = xv.x + xv.y + xv.z + xv.w;
  float sq = xv.x * xv.x + xv.y * xv.y + xv.z * xv.z + xv.w * xv.w;
#pragma unroll
  for (int off = 32; off >= 1; off >>= 1) {
    s += __shfl_xor(s, off);
    sq += __shfl_xor(sq, off);
  }
  float mean = s * (1.f / 256.f);
  float var = sq * (1.f / 256.f) - mean * mean;
  float rstd = rsqrtf(var + 1e-5f);
  float4 gv = *(const float4*)(g + lane * 4);
  float4 bv = *(const float4*)(bta + lane * 4);
  ushort4 ov;
  ov.x = f2bf((xv.x - mean) * rstd * gv.x + bv.x);
  ov.y = f2bf((xv.y - mean) * rstd * gv.y + bv.y);
  ov.z = f2bf((xv.z - mean) * rstd * gv.z + bv.z);
  ov.w = f2bf((xv.w - mean) * rstd * gv.w + bv.w);
  int orow;
  if (WINDOW) {
    int b = token / 196, hw = token % 196;
    int h14 = hw / 14, w14 = hw % 14;
    int wh = h14 / 7, i = h14 % 7, ww = w14 / 7, j = w14 % 7;
    int widx = (b * 2 + wh) * 2 + ww;
    orow = widx * 49 + i * 7 + j - rowbase;
  } else {
    orow = li;
  }
  *(ushort4*)(out + (size_t)orow * 256 + lane * 4) = ov;
}

// ---------------------------------------------------------------------------
// MFMA attention: one WAVE per (window, head); 4 independent waves per block,
// no __syncthreads. QK^T: S[q][t] = sum_d Q[q][d] K[t][d] (16 MFMA, K-dim=32).
// Softmax in-register (rows live in 16-lane groups). PV via O^T = VT x P.
__global__ __launch_bounds__(256) void k_attention(const unsigned short* __restrict__ qkv,
                                                   const float* __restrict__ rpb,
                                                   unsigned short* __restrict__ o) {
  __shared__ unsigned short Kl[4][64 * 40];   // [tok][d], row stride 40 elem (80B)
  __shared__ unsigned short VTl[4][32 * 72];  // [d][tok], row stride 72 elem (144B)
  __shared__ unsigned short Pl[4][64 * 72];   // [q][tok], row stride 72 elem
  __shared__ float rpbl[4][176];

  const int t = threadIdx.x;
  const int w4 = t >> 6, lane = t & 63;
  const int l15 = lane & 15, g = lane >> 4;
  const int gw = blockIdx.x * 4 + w4;
  const int lw = gw >> 3, head = gw & 7;

  unsigned short* K_ = Kl[w4];
  unsigned short* VT_ = VTl[w4];
  unsigned short* P_ = Pl[w4];
  float* rpb_ = rpbl[w4];

  const size_t baseq = (size_t)lw * 49 * 768 + head * 32;

  // ---- stage rpb column for this head
  for (int e = lane; e < 169; e += 64) rpb_[e] = rpb[e * 8 + head];

  // ---- zero VT pad (tok 49..63 and 64..71 tail region stays unread)
  for (int e = lane; e < 512; e += 64) {
    int d = e >> 4, tk = 48 + (e & 15);
    if ((e & 15) != 0) VT_[d * 72 + tk] = 0;
  }

  // ---- stage K [tok][d] and V^T [d][tok]
  for (int e = lane; e < 784; e += 64) {       // 49*16 u32 loads (2 elems each)
    int tok = e >> 4, dp = e & 15;
    unsigned kv = *(const unsigned*)(qkv + baseq + 256 + (size_t)tok * 768 + dp * 2);
    *(unsigned*)&K_[tok * 40 + dp * 2] = kv;
    unsigned vv = *(const unsigned*)(qkv + baseq + 512 + (size_t)tok * 768 + dp * 2);
    VT_[(dp * 2 + 0) * 72 + tok] = (unsigned short)(vv & 0xffffu);
    VT_[(dp * 2 + 1) * 72 + tok] = (unsigned short)(vv >> 16);
  }

  // ---- QK^T: af from global (A-frag = 16B/lane), bf from K LDS
  ffrag4 acc[4][4] = {};
  {
    bfrag8 af[4], bfr[4];
#pragma unroll
    for (int qi = 0; qi < 4; ++qi)
      af[qi] = *(const bfrag8*)(qkv + baseq + (size_t)(16 * qi + l15) * 768 + g * 8);
#pragma unroll
    for (int kj = 0; kj < 4; ++kj)
      bfr[kj] = *(const bfrag8*)&K_[(16 * kj + l15) * 40 + g * 8];
#pragma unroll
    for (int qi = 0; qi < 4; ++qi)
#pragma unroll
      for (int kj = 0; kj < 4; ++kj)
        acc[qi][kj] = __builtin_amdgcn_mfma_f32_16x16x32_bf16(af[qi], bfr[kj], acc[qi][kj], 0, 0, 0);
  }

  // ---- softmax (+ scale + relative position bias), write P (bf16) to LDS
  const float scale = 0.17677669529663687f;    // 1/sqrt(32)
  int kc[4];
  bool kvalid[4];
#pragma unroll
  for (int kj = 0; kj < 4; ++kj) {
    int c = 16 * kj + l15;
    kc[kj] = 13 * (c / 7) + (c % 7);
    kvalid[kj] = (c < 49);
  }
#pragma unroll
  for (int qi = 0; qi < 4; ++qi) {
#pragma unroll
    for (int j = 0; j < 4; ++j) {
      int q = 16 * qi + 4 * g + j;
      int qc = 13 * (q / 7) + (q % 7);
      float tv[4];
#pragma unroll
      for (int kj = 0; kj < 4; ++kj)
        tv[kj] = kvalid[kj] ? (acc[qi][kj][j] * scale + rpb_[qc - kc[kj] + 84]) : -INFINITY;
      float mx = fmaxf(fmaxf(tv[0], tv[1]), fmaxf(tv[2], tv[3]));
#pragma unroll
      for (int off = 8; off >= 1; off >>= 1) mx = fmaxf(mx, __shfl_xor(mx, off));
      float p[4], sum = 0.f;
#pragma unroll
      for (int kj = 0; kj < 4; ++kj) {
        p[kj] = kvalid[kj] ? __expf(tv[kj] - mx) : 0.f;
        sum += p[kj];
      }
#pragma unroll
      for (int off = 8; off >= 1; off >>= 1) sum += __shfl_xor(sum, off);
      float inv = 1.0f / sum;
      if (q < 49) {
#pragma unroll
        for (int kj = 0; kj < 4; ++kj)
          P_[q * 72 + 16 * kj + l15] = f2bf(p[kj] * inv);
      }
    }
  }

  // ---- O^T = VT x P  (row=d, col=q, k=tok in two 32-steps)
  ffrag4 accO[2][4] = {};
#pragma unroll
  for (int kk = 0; kk < 64; kk += 32) {
    bfrag8 af2[2], bf2[4];
#pragma unroll
    for (int ti = 0; ti < 2; ++ti)
      af2[ti] = *(const bfrag8*)&VT_[(16 * ti + l15) * 72 + kk + g * 8];
#pragma unroll
    for (int qj = 0; qj < 4; ++qj)
      bf2[qj] = *(const bfrag8*)&P_[(16 * qj + l15) * 72 + kk + g * 8];
#pragma unroll
    for (int ti = 0; ti < 2; ++ti)
#pragma unroll
      for (int qj = 0; qj < 4; ++qj)
        accO[ti][qj] = __builtin_amdgcn_mfma_f32_16x16x32_bf16(af2[ti], bf2[qj], accO[ti][qj], 0, 0, 0);
  }

  // ---- write O: lane holds O[q][d], d = 16ti + 4g + j (j packs ushort4)
#pragma unroll
  for (int qj = 0; qj < 4; ++qj) {
    int q = 16 * qj + l15;
    if (q < 49) {
#pragma unroll
      for (int ti = 0; ti < 2; ++ti) {
        ushort4 ov;
        ov.x = f2bf(accO[ti][qj][0]);
        ov.y = f2bf(accO[ti][qj][1]);
        ov.z = f2bf(accO[ti][qj][2]);
        ov.w = f2bf(accO[ti][qj][3]);
        *(ushort4*)(o + ((size_t)lw * 49 + q) * 256 + head * 32 + 16 * ti + 4 * g) = ov;
      }
    }
  }
}

// ---------------------------------------------------------------------------
__global__ __launch_bounds__(256) void k_pool(const float* __restrict__ tok,
                                              float* __restrict__ pooled) {
  int b = blockIdx.x, c = threadIdx.x;
  float s = 0.f;
  for (int hw = 0; hw < 196; ++hw) s += tok[((size_t)b * 196 + hw) * 256 + c];
  pooled[b * 256 + c] = s * (1.f / 196.f);
}

__global__ __launch_bounds__(64) void k_head(const float* __restrict__ pooled,
                                             const float* __restrict__ w,
                                             const float* __restrict__ bias,
                                             float* __restrict__ out) {
  int b = blockIdx.x, t = threadIdx.x;
  if (t < 7) {
    float s = bias[t];
    for (int c = 0; c < 256; ++c) s = fmaf(pooled[b * 256 + c], w[c * 7 + t], s);
    out[b * 7 + t] = s;
  }
}

// ---------------------------------------------------------------------------
extern "C" void kernel_launch(void* const* d_in, const int* in_sizes, int n_in,
                              void* d_out, int out_size, void* d_ws, size_t ws_size,
                              hipStream_t stream) {
  const float* x      = (const float*)d_in[0];
  const float* conv_w = (const float*)d_in[1];
  const float* conv_b = (const float*)d_in[2];
  const float* ln1_g  = (const float*)d_in[3];
  const float* ln1_b  = (const float*)d_in[4];
  const float* qkv_w  = (const float*)d_in[5];
  const float* qkv_b  = (const float*)d_in[6];
  const float* rpb    = (const float*)d_in[7];
  const float* proj_w = (const float*)d_in[8];
  const float* proj_b = (const float*)d_in[9];
  const float* ln2_g  = (const float*)d_in[10];
  const float* ln2_b  = (const float*)d_in[11];
  const float* fc1_w  = (const float*)d_in[12];
  const float* fc1_b  = (const float*)d_in[13];
  const float* fc2_w  = (const float*)d_in[14];
  const float* fc2_b  = (const float*)d_in[15];
  const float* fco_w  = (const float*)d_in[16];
  const float* fco_b  = (const float*)d_in[17];
  float* out = (float*)d_out;
  char* p = (char*)d_ws;

  float* tok = (float*)p;                 p += (size_t)MTOT * 256 * 4;
  unsigned short* Bbuf = (unsigned short*)p; p += (size_t)CHROWS * 1024 * 2;
  unsigned short* Abuf = (unsigned short*)p; p += (size_t)CHROWS * 256 * 2;
  unsigned short* Cbuf = (unsigned short*)p; p += (size_t)CHROWS * 256 * 2;
  unsigned short* cwB  = (unsigned short*)p; p += 65536 * 2;
  unsigned short* qkvT = (unsigned short*)p; p += 196608 * 2;
  unsigned short* projT= (unsigned short*)p; p += 65536 * 2;
  unsigned short* fc1T = (unsigned short*)p; p += 262144 * 2;
  unsigned short* fc2T = (unsigned short*)p; p += 262144 * 2;
  float* pool = (float*)p;                p += 65536 * 4;
  unsigned short* xt = Bbuf;

  k_cast<<<256, 256, 0, stream>>>(conv_w, cwB, 65536);
  k_wtrans<<<dim3(8, 24), 256, 0, stream>>>(qkv_w, qkvT, 256, 768);
  k_wtrans<<<dim3(8, 8), 256, 0, stream>>>(proj_w, projT, 256, 256);
  k_wtrans<<<dim3(8, 32), 256, 0, stream>>>(fc1_w, fc1T, 256, 1024);
  k_wtrans<<<dim3(32, 8), 256, 0, stream>>>(fc2_w, fc2T, 1024, 256);

  k_transpose_x<<<dim3(BATCH, 7, 8), 256, 0, stream>>>(x, xt);
  k_gemm_mfma<4><<<dim3(MTOT / BM, 256 / BN), 256, 0, stream>>>(xt, cwB, conv_b, tok, 0, 256, 256);

  for (int c = 0; c < 1024 / CHW; ++c) {
    const int rowbase = c * CHROWS;
    k_layernorm<true><<<CHROWS / 4, 256, 0, stream>>>(tok, ln1_g, ln1_b, Abuf, rowbase);
    k_gemm_mfma<0><<<dim3(CHROWS / BM, 768 / BN), 256, 0, stream>>>(Abuf, qkvT, qkv_b, Bbuf, 0, 768, 256);
    k_attention<<<CHW * 8 / 4, 256, 0, stream>>>(Bbuf, rpb, Cbuf);
    k_gemm_mfma<2><<<dim3(CHROWS / BM, 256 / BN), 256, 0, stream>>>(Cbuf, projT, proj_b, tok, rowbase, 256, 256);
    k_layernorm<false><<<CHROWS / 4, 256, 0, stream>>>(tok, ln2_g, ln2_b, Abuf, rowbase);
    k_gemm_mfma<1><<<dim3(CHROWS / BM, 1024 / BN), 256, 0, stream>>>(Abuf, fc1T, fc1_b, Bbuf, 0, 1024, 256);
    k_gemm_mfma<3><<<dim3(CHROWS / BM, 256 / BN), 256, 0, stream>>>(Bbuf, fc2T, fc2_b, tok, rowbase, 256, 1024);
  }

  k_pool<<<BATCH, 256, 0, stream>>>(tok, pool);
  k_head<<<BATCH, 64, 0, stream>>>(pool, fco_w, fco_b, out);
}

// Round 5
// 400.939 us; speedup vs baseline: 4.5929x; 1.3936x over previous
//
#include <hip/hip_runtime.h>
#include <math.h>

#define NHEADS 8
#define BATCH  256
#define HWTOK  196
#define MTOT   50176          // 1024 windows * 49

#define BM 128
#define BN 128
#define BK 64

typedef short bfrag8 __attribute__((ext_vector_type(8)));
typedef float ffrag4 __attribute__((ext_vector_type(4)));

// ---------------------------------------------------------------------------
__device__ __forceinline__ unsigned short f2bf(float f) {
  union { float f; unsigned u; } v; v.f = f;
  unsigned r = v.u + 0x7fffu + ((v.u >> 16) & 1u);   // RNE
  return (unsigned short)(r >> 16);
}
__device__ __forceinline__ float bf2f(unsigned short b) {
  union { unsigned u; float f; } v; v.u = ((unsigned)b) << 16;
  return v.f;
}
__device__ __forceinline__ float gelu_exact(float x) {
  return 0.5f * x * (1.0f + erff(x * 0.70710678118654752f));
}
// window-major global row m -> token-major global row
__device__ __forceinline__ int window_reverse_row(int m) {
  int widx = m / 49, pos = m % 49;
  int b = widx >> 2, wh = (widx >> 1) & 1, ww = widx & 1;
  int i = pos / 7, j = pos % 7;
  return b * 196 + (wh * 7 + i) * 14 + (ww * 7 + j);
}

__device__ __forceinline__ void gload16(const void* g, void* l) {
  __builtin_amdgcn_global_load_lds(
      (const __attribute__((address_space(1))) void*)g,
      (__attribute__((address_space(3))) void*)l, 16, 0, 0);
}

// stage one 128x64 A-tile and B-tile into LDS (linear layout, wave-uniform base)
__device__ __forceinline__ void stage_tile(const unsigned short* __restrict__ A,
                                           const unsigned short* __restrict__ BT,
                                           unsigned short* As, unsigned short* Bs,
                                           int m0, int n0, int K, int k0,
                                           int w, int rA, int kin) {
#pragma unroll
  for (int i = 0; i < 4; ++i) {
    const int seg = i * 4 + w;          // wave-uniform 0..15
    const int row = seg * 8 + rA;       // 0..127
    gload16(A + (size_t)(m0 + row) * K + k0 + kin, (char*)As + seg * 1024);
    gload16(BT + (size_t)(n0 + row) * K + k0 + kin, (char*)Bs + seg * 1024);
  }
}

// ---------------------------------------------------------------------------
// bf16 MFMA GEMM: A [M][K] bf16, BT [N][K] bf16, 128x128 tile, BK=64,
// 2-phase prefetch: double-buffered LDS, stage(k+1) issued before compute(k),
// single __syncthreads per K-step (drains prefetch that overlapped MFMA).
// EPI 0: Cout(bf16) = acc+bias ; 1: gelu ; 2: f32 RMW via window_reverse ;
// EPI 3: f32 RMW at rowbase+m ; 4: f32 store
template <int EPI>
__global__ __launch_bounds__(256) void k_gemm_mfma(const unsigned short* __restrict__ A,
                                                   const unsigned short* __restrict__ BT,
                                                   const float* __restrict__ bias,
                                                   void* __restrict__ Cout,
                                                   int rowbase, int N, int K) {
  __shared__ __align__(128) unsigned short As[2][BM * BK];
  __shared__ __align__(128) unsigned short Bs[2][BN * BK];
  const int t = threadIdx.x;
  const int lane = t & 63, w = t >> 6;
  const int wr = w >> 1, wc = w & 1;
  const int m0 = blockIdx.x * BM, n0 = blockIdx.y * BN;
  const int rA = lane >> 3;
  const int kin = (lane & 7) * 8;
  ffrag4 acc[4][4] = {};

  stage_tile(A, BT, As[0], Bs[0], m0, n0, K, 0, w, rA, kin);
  __syncthreads();
  int cur = 0;
  for (int k0 = 0; k0 < K; k0 += BK) {
    if (k0 + BK < K)
      stage_tile(A, BT, As[cur ^ 1], Bs[cur ^ 1], m0, n0, K, k0 + BK, w, rA, kin);
#pragma unroll
    for (int kk = 0; kk < BK; kk += 32) {
      bfrag8 af[4], bfr[4];
#pragma unroll
      for (int mi = 0; mi < 4; ++mi) {
        int row = wr * 64 + mi * 16 + (lane & 15);
        af[mi] = *(const bfrag8*)&As[cur][row * BK + kk + (lane >> 4) * 8];
      }
#pragma unroll
      for (int ni = 0; ni < 4; ++ni) {
        int col = wc * 64 + ni * 16 + (lane & 15);
        bfr[ni] = *(const bfrag8*)&Bs[cur][col * BK + kk + (lane >> 4) * 8];
      }
#pragma unroll
      for (int mi = 0; mi < 4; ++mi)
#pragma unroll
        for (int ni = 0; ni < 4; ++ni)
          acc[mi][ni] = __builtin_amdgcn_mfma_f32_16x16x32_bf16(af[mi], bfr[ni], acc[mi][ni], 0, 0, 0);
    }
    __syncthreads();    // drains this iter's prefetch (overlapped with MFMA above)
    cur ^= 1;
  }

  const int cr = (lane >> 4) * 4;
  const int cc = lane & 15;
  float bv[4];
#pragma unroll
  for (int ni = 0; ni < 4; ++ni) bv[ni] = bias[n0 + wc * 64 + ni * 16 + cc];
#pragma unroll
  for (int mi = 0; mi < 4; ++mi) {
#pragma unroll
    for (int j = 0; j < 4; ++j) {
      const int m = m0 + wr * 64 + mi * 16 + cr + j;
      int row;
      if (EPI == 2) row = window_reverse_row(rowbase + m);
      else if (EPI == 3) row = rowbase + m;
      else row = m;
#pragma unroll
      for (int ni = 0; ni < 4; ++ni) {
        const int n = n0 + wc * 64 + ni * 16 + cc;
        float v = acc[mi][ni][j] + bv[ni];
        if (EPI == 1) v = gelu_exact(v);
        if (EPI == 0 || EPI == 1) {
          ((unsigned short*)Cout)[(size_t)m * N + n] = f2bf(v);
        } else if (EPI == 4) {
          ((float*)Cout)[(size_t)row * N + n] = v;
        } else {
          float* p = (float*)Cout + (size_t)row * N + n;
          *p += v;
        }
      }
    }
  }
}

// ---------------------------------------------------------------------------
__global__ __launch_bounds__(256) void k_wtrans(const float* __restrict__ w,
                                                unsigned short* __restrict__ wt,
                                                int K, int N) {
  __shared__ float tile[32][33];
  int k0 = blockIdx.x * 32, n0 = blockIdx.y * 32;
  int tx = threadIdx.x & 31, ty = threadIdx.x >> 5;
#pragma unroll
  for (int r = 0; r < 4; ++r)
    tile[ty + r * 8][tx] = w[(size_t)(k0 + ty + r * 8) * N + n0 + tx];
  __syncthreads();
#pragma unroll
  for (int r = 0; r < 4; ++r)
    wt[(size_t)(n0 + ty + r * 8) * K + k0 + tx] = f2bf(tile[tx][ty + r * 8]);
}

__global__ __launch_bounds__(256) void k_cast(const float* __restrict__ w,
                                              unsigned short* __restrict__ wb, int n) {
  int i = blockIdx.x * 256 + threadIdx.x;
  if (i < n) wb[i] = f2bf(w[i]);
}

__global__ __launch_bounds__(256) void k_transpose_x(const float* __restrict__ x,
                                                     unsigned short* __restrict__ xt) {
  __shared__ float tile[32][33];
  int b = blockIdx.x;
  int hw0 = blockIdx.y * 32;
  int c0 = blockIdx.z * 32;
  int tx = threadIdx.x & 31, ty = threadIdx.x >> 5;
#pragma unroll
  for (int r = 0; r < 4; ++r) {
    int c = c0 + ty + r * 8, hw = hw0 + tx;
    if (hw < HWTOK) tile[ty + r * 8][tx] = x[((size_t)b * 256 + c) * HWTOK + hw];
  }
  __syncthreads();
#pragma unroll
  for (int r = 0; r < 4; ++r) {
    int hw = hw0 + ty + r * 8, c = c0 + tx;
    if (hw < HWTOK) xt[((size_t)b * HWTOK + hw) * 256 + c] = f2bf(tile[tx][ty + r * 8]);
  }
}

// ---------------------------------------------------------------------------
template <bool WINDOW>
__global__ __launch_bounds__(256) void k_layernorm(const float* __restrict__ in,
                                                   const float* __restrict__ g,
                                                   const float* __restrict__ bta,
                                                   unsigned short* __restrict__ out,
                                                   int rowbase) {
  int wid = threadIdx.x >> 6, lane = threadIdx.x & 63;
  int li = blockIdx.x * 4 + wid;
  int token = rowbase + li;
  const float4 xv = *(const float4*)(in + (size_t)token * 256 + lane * 4);
  float s = xv.x + xv.y + xv.z + xv.w;
  float sq = xv.x * xv.x + xv.y * xv.y + xv.z * xv.z + xv.w * xv.w;
#pragma unroll
  for (int off = 32; off >= 1; off >>= 1) {
    s += __shfl_xor(s, off);
    sq += __shfl_xor(sq, off);
  }
  float mean = s * (1.f / 256.f);
  float var = sq * (1.f / 256.f) - mean * mean;
  float rstd = rsqrtf(var + 1e-5f);
  float4 gv = *(const float4*)(g + lane * 4);
  float4 bv = *(const float4*)(bta + lane * 4);
  ushort4 ov;
  ov.x = f2bf((xv.x - mean) * rstd * gv.x + bv.x);
  ov.y = f2bf((xv.y - mean) * rstd * gv.y + bv.y);
  ov.z = f2bf((xv.z - mean) * rstd * gv.z + bv.z);
  ov.w = f2bf((xv.w - mean) * rstd * gv.w + bv.w);
  int orow;
  if (WINDOW) {
    int b = token / 196, hw = token % 196;
    int h14 = hw / 14, w14 = hw % 14;
    int wh = h14 / 7, i = h14 % 7, ww = w14 / 7, j = w14 % 7;
    int widx = (b * 2 + wh) * 2 + ww;
    orow = widx * 49 + i * 7 + j - rowbase;
  } else {
    orow = li;
  }
  *(ushort4*)(out + (size_t)orow * 256 + lane * 4) = ov;
}

// ---------------------------------------------------------------------------
// MFMA attention: one WAVE per (window, head); 4 independent waves per block.
__global__ __launch_bounds__(256) void k_attention(const unsigned short* __restrict__ qkv,
                                                   const float* __restrict__ rpb,
                                                   unsigned short* __restrict__ o) {
  __shared__ unsigned short Kl[4][64 * 40];
  __shared__ unsigned short VTl[4][32 * 72];
  __shared__ unsigned short Pl[4][64 * 72];
  __shared__ float rpbl[4][176];

  const int t = threadIdx.x;
  const int w4 = t >> 6, lane = t & 63;
  const int l15 = lane & 15, g = lane >> 4;
  const int gw = blockIdx.x * 4 + w4;
  const int lw = gw >> 3, head = gw & 7;

  unsigned short* K_ = Kl[w4];
  unsigned short* VT_ = VTl[w4];
  unsigned short* P_ = Pl[w4];
  float* rpb_ = rpbl[w4];

  const size_t baseq = (size_t)lw * 49 * 768 + head * 32;

  for (int e = lane; e < 169; e += 64) rpb_[e] = rpb[e * 8 + head];

  for (int e = lane; e < 512; e += 64) {
    int d = e >> 4, tk = 48 + (e & 15);
    if ((e & 15) != 0) VT_[d * 72 + tk] = 0;
  }

  for (int e = lane; e < 784; e += 64) {
    int tok = e >> 4, dp = e & 15;
    unsigned kv = *(const unsigned*)(qkv + baseq + 256 + (size_t)tok * 768 + dp * 2);
    *(unsigned*)&K_[tok * 40 + dp * 2] = kv;
    unsigned vv = *(const unsigned*)(qkv + baseq + 512 + (size_t)tok * 768 + dp * 2);
    VT_[(dp * 2 + 0) * 72 + tok] = (unsigned short)(vv & 0xffffu);
    VT_[(dp * 2 + 1) * 72 + tok] = (unsigned short)(vv >> 16);
  }

  ffrag4 acc[4][4] = {};
  {
    bfrag8 af[4], bfr[4];
#pragma unroll
    for (int qi = 0; qi < 4; ++qi)
      af[qi] = *(const bfrag8*)(qkv + baseq + (size_t)(16 * qi + l15) * 768 + g * 8);
#pragma unroll
    for (int kj = 0; kj < 4; ++kj)
      bfr[kj] = *(const bfrag8*)&K_[(16 * kj + l15) * 40 + g * 8];
#pragma unroll
    for (int qi = 0; qi < 4; ++qi)
#pragma unroll
      for (int kj = 0; kj < 4; ++kj)
        acc[qi][kj] = __builtin_amdgcn_mfma_f32_16x16x32_bf16(af[qi], bfr[kj], acc[qi][kj], 0, 0, 0);
  }

  const float scale = 0.17677669529663687f;
  int kc[4];
  bool kvalid[4];
#pragma unroll
  for (int kj = 0; kj < 4; ++kj) {
    int c = 16 * kj + l15;
    kc[kj] = 13 * (c / 7) + (c % 7);
    kvalid[kj] = (c < 49);
  }
#pragma unroll
  for (int qi = 0; qi < 4; ++qi) {
#pragma unroll
    for (int j = 0; j < 4; ++j) {
      int q = 16 * qi + 4 * g + j;
      int qc = 13 * (q / 7) + (q % 7);
      float tv[4];
#pragma unroll
      for (int kj = 0; kj < 4; ++kj)
        tv[kj] = kvalid[kj] ? (acc[qi][kj][j] * scale + rpb_[qc - kc[kj] + 84]) : -INFINITY;
      float mx = fmaxf(fmaxf(tv[0], tv[1]), fmaxf(tv[2], tv[3]));
#pragma unroll
      for (int off = 8; off >= 1; off >>= 1) mx = fmaxf(mx, __shfl_xor(mx, off));
      float p[4], sum = 0.f;
#pragma unroll
      for (int kj = 0; kj < 4; ++kj) {
        p[kj] = kvalid[kj] ? __expf(tv[kj] - mx) : 0.f;
        sum += p[kj];
      }
#pragma unroll
      for (int off = 8; off >= 1; off >>= 1) sum += __shfl_xor(sum, off);
      float inv = 1.0f / sum;
      if (q < 49) {
#pragma unroll
        for (int kj = 0; kj < 4; ++kj)
          P_[q * 72 + 16 * kj + l15] = f2bf(p[kj] * inv);
      }
    }
  }

  ffrag4 accO[2][4] = {};
#pragma unroll
  for (int kk = 0; kk < 64; kk += 32) {
    bfrag8 af2[2], bf2[4];
#pragma unroll
    for (int ti = 0; ti < 2; ++ti)
      af2[ti] = *(const bfrag8*)&VT_[(16 * ti + l15) * 72 + kk + g * 8];
#pragma unroll
    for (int qj = 0; qj < 4; ++qj)
      bf2[qj] = *(const bfrag8*)&P_[(16 * qj + l15) * 72 + kk + g * 8];
#pragma unroll
    for (int ti = 0; ti < 2; ++ti)
#pragma unroll
      for (int qj = 0; qj < 4; ++qj)
        accO[ti][qj] = __builtin_amdgcn_mfma_f32_16x16x32_bf16(af2[ti], bf2[qj], accO[ti][qj], 0, 0, 0);
  }

#pragma unroll
  for (int qj = 0; qj < 4; ++qj) {
    int q = 16 * qj + l15;
    if (q < 49) {
#pragma unroll
      for (int ti = 0; ti < 2; ++ti) {
        ushort4 ov;
        ov.x = f2bf(accO[ti][qj][0]);
        ov.y = f2bf(accO[ti][qj][1]);
        ov.z = f2bf(accO[ti][qj][2]);
        ov.w = f2bf(accO[ti][qj][3]);
        *(ushort4*)(o + ((size_t)lw * 49 + q) * 256 + head * 32 + 16 * ti + 4 * g) = ov;
      }
    }
  }
}

// ---------------------------------------------------------------------------
__global__ __launch_bounds__(256) void k_pool(const float* __restrict__ tok,
                                              float* __restrict__ pooled) {
  int b = blockIdx.x, c = threadIdx.x;
  float s = 0.f;
  for (int hw = 0; hw < 196; ++hw) s += tok[((size_t)b * 196 + hw) * 256 + c];
  pooled[b * 256 + c] = s * (1.f / 196.f);
}

__global__ __launch_bounds__(64) void k_head(const float* __restrict__ pooled,
                                             const float* __restrict__ w,
                                             const float* __restrict__ bias,
                                             float* __restrict__ out) {
  int b = blockIdx.x, t = threadIdx.x;
  if (t < 7) {
    float s = bias[t];
    for (int c = 0; c < 256; ++c) s = fmaf(pooled[b * 256 + c], w[c * 7 + t], s);
    out[b * 7 + t] = s;
  }
}

// ---------------------------------------------------------------------------
extern "C" void kernel_launch(void* const* d_in, const int* in_sizes, int n_in,
                              void* d_out, int out_size, void* d_ws, size_t ws_size,
                              hipStream_t stream) {
  const float* x      = (const float*)d_in[0];
  const float* conv_w = (const float*)d_in[1];
  const float* conv_b = (const float*)d_in[2];
  const float* ln1_g  = (const float*)d_in[3];
  const float* ln1_b  = (const float*)d_in[4];
  const float* qkv_w  = (const float*)d_in[5];
  const float* qkv_b  = (const float*)d_in[6];
  const float* rpb    = (const float*)d_in[7];
  const float* proj_w = (const float*)d_in[8];
  const float* proj_b = (const float*)d_in[9];
  const float* ln2_g  = (const float*)d_in[10];
  const float* ln2_b  = (const float*)d_in[11];
  const float* fc1_w  = (const float*)d_in[12];
  const float* fc1_b  = (const float*)d_in[13];
  const float* fc2_w  = (const float*)d_in[14];
  const float* fc2_b  = (const float*)d_in[15];
  const float* fco_w  = (const float*)d_in[16];
  const float* fco_b  = (const float*)d_in[17];
  float* out = (float*)d_out;
  char* p = (char*)d_ws;

  // Full-M layout needs ~207.5 MB (h1 aliases the dead qkv buffer);
  // chunked (4 chunks) needs ~92 MB (known good). Pick by ws_size.
  const size_t FULL_NEED = 207486976ull;
  const int nch = (ws_size >= FULL_NEED) ? 1 : 4;
  const int chw = 1024 / nch;                 // windows per chunk
  const size_t chrows = (size_t)chw * 49;     // rows per chunk (multiple of 128)

  float* tok = (float*)p;                     p += (size_t)MTOT * 256 * 4;
  unsigned short* Bbuf = (unsigned short*)p;  p += chrows * 1024 * 2;  // xt / qkv / h1
  unsigned short* Abuf = (unsigned short*)p;  p += chrows * 256 * 2;   // LN out
  unsigned short* Cbuf = (unsigned short*)p;  p += chrows * 256 * 2;   // attn out
  unsigned short* cwB  = (unsigned short*)p;  p += 65536 * 2;
  unsigned short* qkvT = (unsigned short*)p;  p += 196608 * 2;
  unsigned short* projT= (unsigned short*)p;  p += 65536 * 2;
  unsigned short* fc1T = (unsigned short*)p;  p += 262144 * 2;
  unsigned short* fc2T = (unsigned short*)p;  p += 262144 * 2;
  float* pool = (float*)p;                    p += 65536 * 4;
  unsigned short* xt = Bbuf;   // x^T lives only before the chunk loop

  k_cast<<<256, 256, 0, stream>>>(conv_w, cwB, 65536);
  k_wtrans<<<dim3(8, 24), 256, 0, stream>>>(qkv_w, qkvT, 256, 768);
  k_wtrans<<<dim3(8, 8), 256, 0, stream>>>(proj_w, projT, 256, 256);
  k_wtrans<<<dim3(8, 32), 256, 0, stream>>>(fc1_w, fc1T, 256, 1024);
  k_wtrans<<<dim3(32, 8), 256, 0, stream>>>(fc2_w, fc2T, 1024, 256);

  k_transpose_x<<<dim3(BATCH, 7, 8), 256, 0, stream>>>(x, xt);
  k_gemm_mfma<4><<<dim3(MTOT / BM, 256 / BN), 256, 0, stream>>>(xt, cwB, conv_b, tok, 0, 256, 256);

  for (int c = 0; c < nch; ++c) {
    const int rowbase = c * (int)chrows;
    k_layernorm<true><<<chrows / 4, 256, 0, stream>>>(tok, ln1_g, ln1_b, Abuf, rowbase);
    k_gemm_mfma<0><<<dim3(chrows / BM, 768 / BN), 256, 0, stream>>>(Abuf, qkvT, qkv_b, Bbuf, 0, 768, 256);
    k_attention<<<chw * 2, 256, 0, stream>>>(Bbuf, rpb, Cbuf);
    k_gemm_mfma<2><<<dim3(chrows / BM, 256 / BN), 256, 0, stream>>>(Cbuf, projT, proj_b, tok, rowbase, 256, 256);
    k_layernorm<false><<<chrows / 4, 256, 0, stream>>>(tok, ln2_g, ln2_b, Abuf, rowbase);
    k_gemm_mfma<1><<<dim3(chrows / BM, 1024 / BN), 256, 0, stream>>>(Abuf, fc1T, fc1_b, Bbuf, 0, 1024, 256);
    k_gemm_mfma<3><<<dim3(chrows / BM, 256 / BN), 256, 0, stream>>>(Bbuf, fc2T, fc2_b, tok, rowbase, 256, 1024);
  }

  k_pool<<<BATCH, 256, 0, stream>>>(tok, pool);
  k_head<<<BATCH, 64, 0, stream>>>(pool, fco_w, fco_b, out);
}

// Round 8
// 371.710 us; speedup vs baseline: 4.9540x; 1.0786x over previous
//
#include <hip/hip_runtime.h>
#include <math.h>

#define NHEADS 8
#define BATCH  256
#define HWTOK  196
#define MTOT   50176          // 1024 windows * 49

#define BM 128
#define BN 128
#define BK 64

typedef short bfrag8 __attribute__((ext_vector_type(8)));
typedef float ffrag4 __attribute__((ext_vector_type(4)));

// ---------------------------------------------------------------------------
__device__ __forceinline__ unsigned short f2bf(float f) {
  union { float f; unsigned u; } v; v.f = f;
  unsigned r = v.u + 0x7fffu + ((v.u >> 16) & 1u);   // RNE
  return (unsigned short)(r >> 16);
}
__device__ __forceinline__ float bf2f(unsigned short b) {
  union { unsigned u; float f; } v; v.u = ((unsigned)b) << 16;
  return v.f;
}
__device__ __forceinline__ float gelu_exact(float x) {
  return 0.5f * x * (1.0f + erff(x * 0.70710678118654752f));
}
__device__ __forceinline__ int window_reverse_row(int m) {
  int widx = m / 49, pos = m % 49;
  int b = widx >> 2, wh = (widx >> 1) & 1, ww = widx & 1;
  int i = pos / 7, j = pos % 7;
  return b * 196 + (wh * 7 + i) * 14 + (ww * 7 + j);
}

__device__ __forceinline__ void gload16(const void* g, void* l) {
  __builtin_amdgcn_global_load_lds(
      (const __attribute__((address_space(1))) void*)g,
      (__attribute__((address_space(3))) void*)l, 16, 0, 0);
}

// ---------------------------------------------------------------------------
// bf16 MFMA GEMM: A [M][K] bf16, BT [N][K] bf16, 128x128 tile, BK=64,
// 2-phase prefetch, XOR-swizzled LDS (source-side pre-swizzle, rule #21),
// L2-friendly transposed block order, vectorized bf16 epilogue via LDS bounce.
// LDS byte map: A0 @0, A1 @16384, B0 @32768, B1 @49152 (tile = 16384 B).
// EPI 0: Cout(bf16)=acc+bias ; 1: gelu ; 2: f32 RMW window_reverse ;
// 3: f32 RMW rowbase+m ; 4: f32 store
template <int EPI>
__global__ __launch_bounds__(256) void k_gemm_mfma(const unsigned short* __restrict__ A,
                                                   const unsigned short* __restrict__ BT,
                                                   const float* __restrict__ bias,
                                                   void* __restrict__ Cout,
                                                   int rowbase, int N, int K, int nMt) {
  __shared__ __align__(128) unsigned short S[32768];   // 64 KB
  const int t = threadIdx.x;
  const int lane = t & 63, w = t >> 6;
  const int wr = w >> 1, wc = w & 1;
  const int m_t = blockIdx.x % nMt, n_t = blockIdx.x / nMt;
  const int m0 = m_t * BM, n0 = n_t * BN;
  const int l15 = lane & 15;
  const int sw = (lane & 7) << 3;                 // read-side XOR (elements)
  const int rA = lane >> 3;                       // staging row within segment
  const int kin = (((lane & 7) ^ rA) << 3);       // swizzled source col (elems)
  ffrag4 acc[4][4] = {};

  // stage K-tile k0 into buffer buf; tile stride 16384 BYTES per buffer
#define STAGE(buf, k0_)                                                         \
  {                                                                             \
    _Pragma("unroll")                                                           \
    for (int i = 0; i < 4; ++i) {                                               \
      const int seg = i * 4 + w;                                                \
      const int row = seg * 8 + rA;                                             \
      gload16(A + (size_t)(m0 + row) * K + (k0_) + kin,                         \
              (char*)S + (buf) * 16384 + seg * 1024);                           \
      gload16(BT + (size_t)(n0 + row) * K + (k0_) + kin,                        \
              (char*)S + 32768 + (buf) * 16384 + seg * 1024);                   \
    }                                                                           \
  }

  STAGE(0, 0);
  __syncthreads();
  int cur = 0;
  for (int k0 = 0; k0 < K; k0 += BK) {
    if (k0 + BK < K) STAGE(cur ^ 1, k0 + BK);
    const int ab = cur * 8192, bb = 16384 + cur * 8192;   // u16 element offsets
#pragma unroll
    for (int kk = 0; kk < BK; kk += 32) {
      bfrag8 af[4], bfr[4];
      const int colA = (kk + (lane >> 4) * 8) ^ sw;
#pragma unroll
      for (int mi = 0; mi < 4; ++mi) {
        int row = wr * 64 + mi * 16 + l15;
        af[mi] = *(const bfrag8*)&S[ab + row * BK + colA];
      }
#pragma unroll
      for (int ni = 0; ni < 4; ++ni) {
        int col = wc * 64 + ni * 16 + l15;
        bfr[ni] = *(const bfrag8*)&S[bb + col * BK + colA];
      }
#pragma unroll
      for (int mi = 0; mi < 4; ++mi)
#pragma unroll
        for (int ni = 0; ni < 4; ++ni)
          acc[mi][ni] = __builtin_amdgcn_mfma_f32_16x16x32_bf16(af[mi], bfr[ni], acc[mi][ni], 0, 0, 0);
    }
    __syncthreads();    // drains this iter's prefetch (overlapped with MFMA)
    cur ^= 1;
  }
#undef STAGE

  const int cr = (lane >> 4) * 4;
  const int cc = l15;
  float bv[4];
#pragma unroll
  for (int ni = 0; ni < 4; ++ni) bv[ni] = bias[n0 + wc * 64 + ni * 16 + cc];

  if (EPI == 0 || EPI == 1) {
    // bounce through LDS for vectorized 16B stores
#pragma unroll
    for (int mi = 0; mi < 4; ++mi) {
#pragma unroll
      for (int j = 0; j < 4; ++j) {
        const int ml = wr * 64 + mi * 16 + cr + j;
#pragma unroll
        for (int ni = 0; ni < 4; ++ni) {
          const int nl = wc * 64 + ni * 16 + cc;
          float v = acc[mi][ni][j] + bv[ni];
          if (EPI == 1) v = gelu_exact(v);
          S[ml * 128 + nl] = f2bf(v);
        }
      }
    }
    __syncthreads();
#pragma unroll
    for (int r = 0; r < 8; ++r) {
      const int flat = (r * 256 + t) * 8;          // u16 elements
      const int ml = flat >> 7, nl = flat & 127;
      uint4 vv = *(const uint4*)&S[flat];
      *(uint4*)((unsigned short*)Cout + (size_t)(m0 + ml) * N + n0 + nl) = vv;
    }
  } else {
#pragma unroll
    for (int mi = 0; mi < 4; ++mi) {
#pragma unroll
      for (int j = 0; j < 4; ++j) {
        const int m = m0 + wr * 64 + mi * 16 + cr + j;
        int row;
        if (EPI == 2) row = window_reverse_row(rowbase + m);
        else if (EPI == 3) row = rowbase + m;
        else row = m;
#pragma unroll
        for (int ni = 0; ni < 4; ++ni) {
          const int n = n0 + wc * 64 + ni * 16 + cc;
          float v = acc[mi][ni][j] + bv[ni];
          if (EPI == 4) {
            ((float*)Cout)[(size_t)row * N + n] = v;
          } else {
            float* p = (float*)Cout + (size_t)row * N + n;
            *p += v;
          }
        }
      }
    }
  }
}

// ---------------------------------------------------------------------------
__global__ __launch_bounds__(256) void k_wtrans(const float* __restrict__ w,
                                                unsigned short* __restrict__ wt,
                                                int K, int N) {
  __shared__ float tile[32][33];
  int k0 = blockIdx.x * 32, n0 = blockIdx.y * 32;
  int tx = threadIdx.x & 31, ty = threadIdx.x >> 5;
#pragma unroll
  for (int r = 0; r < 4; ++r)
    tile[ty + r * 8][tx] = w[(size_t)(k0 + ty + r * 8) * N + n0 + tx];
  __syncthreads();
#pragma unroll
  for (int r = 0; r < 4; ++r)
    wt[(size_t)(n0 + ty + r * 8) * K + k0 + tx] = f2bf(tile[tx][ty + r * 8]);
}

__global__ __launch_bounds__(256) void k_cast(const float* __restrict__ w,
                                              unsigned short* __restrict__ wb, int n) {
  int i = blockIdx.x * 256 + threadIdx.x;
  if (i < n) wb[i] = f2bf(w[i]);
}

__global__ __launch_bounds__(256) void k_transpose_x(const float* __restrict__ x,
                                                     unsigned short* __restrict__ xt) {
  __shared__ float tile[32][33];
  int b = blockIdx.x;
  int hw0 = blockIdx.y * 32;
  int c0 = blockIdx.z * 32;
  int tx = threadIdx.x & 31, ty = threadIdx.x >> 5;
#pragma unroll
  for (int r = 0; r < 4; ++r) {
    int c = c0 + ty + r * 8, hw = hw0 + tx;
    if (hw < HWTOK) tile[ty + r * 8][tx] = x[((size_t)b * 256 + c) * HWTOK + hw];
  }
  __syncthreads();
#pragma unroll
  for (int r = 0; r < 4; ++r) {
    int hw = hw0 + ty + r * 8, c = c0 + tx;
    if (hw < HWTOK) xt[((size_t)b * HWTOK + hw) * 256 + c] = f2bf(tile[tx][ty + r * 8]);
  }
}

// ---------------------------------------------------------------------------
template <bool WINDOW>
__global__ __launch_bounds__(256) void k_layernorm(const float* __restrict__ in,
                                                   const float* __restrict__ g,
                                                   const float* __restrict__ bta,
                                                   unsigned short* __restrict__ out,
                                                   int rowbase) {
  int wid = threadIdx.x >> 6, lane = threadIdx.x & 63;
  int li = blockIdx.x * 4 + wid;
  int token = rowbase + li;
  const float4 xv = *(const float4*)(in + (size_t)token * 256 + lane * 4);
  float s = xv.x + xv.y + xv.z + xv.w;
  float sq = xv.x * xv.x + xv.y * xv.y + xv.z * xv.z + xv.w * xv.w;
#pragma unroll
  for (int off = 32; off >= 1; off >>= 1) {
    s += __shfl_xor(s, off);
    sq += __shfl_xor(sq, off);
  }
  float mean = s * (1.f / 256.f);
  float var = sq * (1.f / 256.f) - mean * mean;
  float rstd = rsqrtf(var + 1e-5f);
  float4 gv = *(const float4*)(g + lane * 4);
  float4 bv = *(const float4*)(bta + lane * 4);
  ushort4 ov;
  ov.x = f2bf((xv.x - mean) * rstd * gv.x + bv.x);
  ov.y = f2bf((xv.y - mean) * rstd * gv.y + bv.y);
  ov.z = f2bf((xv.z - mean) * rstd * gv.z + bv.z);
  ov.w = f2bf((xv.w - mean) * rstd * gv.w + bv.w);
  int orow;
  if (WINDOW) {
    int b = token / 196, hw = token % 196;
    int h14 = hw / 14, w14 = hw % 14;
    int wh = h14 / 7, i = h14 % 7, ww = w14 / 7, j = w14 % 7;
    int widx = (b * 2 + wh) * 2 + ww;
    orow = widx * 49 + i * 7 + j - rowbase;
  } else {
    orow = li;
  }
  *(ushort4*)(out + (size_t)orow * 256 + lane * 4) = ov;
}

// ---------------------------------------------------------------------------
// MFMA attention: one WAVE per (window, head); 4 independent waves per block.
__global__ __launch_bounds__(256) void k_attention(const unsigned short* __restrict__ qkv,
                                                   const float* __restrict__ rpb,
                                                   unsigned short* __restrict__ o) {
  __shared__ unsigned short Kl[4][64 * 40];
  __shared__ unsigned short VTl[4][32 * 72];
  __shared__ unsigned short Pl[4][64 * 72];
  __shared__ float rpbl[4][176];

  const int t = threadIdx.x;
  const int w4 = t >> 6, lane = t & 63;
  const int l15 = lane & 15, g = lane >> 4;
  const int gw = blockIdx.x * 4 + w4;
  const int lw = gw >> 3, head = gw & 7;

  unsigned short* K_ = Kl[w4];
  unsigned short* VT_ = VTl[w4];
  unsigned short* P_ = Pl[w4];
  float* rpb_ = rpbl[w4];

  const size_t baseq = (size_t)lw * 49 * 768 + head * 32;

  for (int e = lane; e < 169; e += 64) rpb_[e] = rpb[e * 8 + head];

  for (int e = lane; e < 512; e += 64) {
    int d = e >> 4, tk = 48 + (e & 15);
    if ((e & 15) != 0) VT_[d * 72 + tk] = 0;
  }

  for (int e = lane; e < 784; e += 64) {
    int tok = e >> 4, dp = e & 15;
    unsigned kv = *(const unsigned*)(qkv + baseq + 256 + (size_t)tok * 768 + dp * 2);
    *(unsigned*)&K_[tok * 40 + dp * 2] = kv;
    unsigned vv = *(const unsigned*)(qkv + baseq + 512 + (size_t)tok * 768 + dp * 2);
    VT_[(dp * 2 + 0) * 72 + tok] = (unsigned short)(vv & 0xffffu);
    VT_[(dp * 2 + 1) * 72 + tok] = (unsigned short)(vv >> 16);
  }

  ffrag4 acc[4][4] = {};
  {
    bfrag8 af[4], bfr[4];
#pragma unroll
    for (int qi = 0; qi < 4; ++qi)
      af[qi] = *(const bfrag8*)(qkv + baseq + (size_t)(16 * qi + l15) * 768 + g * 8);
#pragma unroll
    for (int kj = 0; kj < 4; ++kj)
      bfr[kj] = *(const bfrag8*)&K_[(16 * kj + l15) * 40 + g * 8];
#pragma unroll
    for (int qi = 0; qi < 4; ++qi)
#pragma unroll
      for (int kj = 0; kj < 4; ++kj)
        acc[qi][kj] = __builtin_amdgcn_mfma_f32_16x16x32_bf16(af[qi], bfr[kj], acc[qi][kj], 0, 0, 0);
  }

  const float scale = 0.17677669529663687f;
  int kc[4];
  bool kvalid[4];
#pragma unroll
  for (int kj = 0; kj < 4; ++kj) {
    int c = 16 * kj + l15;
    kc[kj] = 13 * (c / 7) + (c % 7);
    kvalid[kj] = (c < 49);
  }
#pragma unroll
  for (int qi = 0; qi < 4; ++qi) {
#pragma unroll
    for (int j = 0; j < 4; ++j) {
      int q = 16 * qi + 4 * g + j;
      int qc = 13 * (q / 7) + (q % 7);
      float tv[4];
#pragma unroll
      for (int kj = 0; kj < 4; ++kj)
        tv[kj] = kvalid[kj] ? (acc[qi][kj][j] * scale + rpb_[qc - kc[kj] + 84]) : -INFINITY;
      float mx = fmaxf(fmaxf(tv[0], tv[1]), fmaxf(tv[2], tv[3]));
#pragma unroll
      for (int off = 8; off >= 1; off >>= 1) mx = fmaxf(mx, __shfl_xor(mx, off));
      float p[4], sum = 0.f;
#pragma unroll
      for (int kj = 0; kj < 4; ++kj) {
        p[kj] = kvalid[kj] ? __expf(tv[kj] - mx) : 0.f;
        sum += p[kj];
      }
#pragma unroll
      for (int off = 8; off >= 1; off >>= 1) sum += __shfl_xor(sum, off);
      float inv = 1.0f / sum;
      if (q < 49) {
#pragma unroll
        for (int kj = 0; kj < 4; ++kj)
          P_[q * 72 + 16 * kj + l15] = f2bf(p[kj] * inv);
      }
    }
  }

  ffrag4 accO[2][4] = {};
#pragma unroll
  for (int kk = 0; kk < 64; kk += 32) {
    bfrag8 af2[2], bf2[4];
#pragma unroll
    for (int ti = 0; ti < 2; ++ti)
      af2[ti] = *(const bfrag8*)&VT_[(16 * ti + l15) * 72 + kk + g * 8];
#pragma unroll
    for (int qj = 0; qj < 4; ++qj)
      bf2[qj] = *(const bfrag8*)&P_[(16 * qj + l15) * 72 + kk + g * 8];
#pragma unroll
    for (int ti = 0; ti < 2; ++ti)
#pragma unroll
      for (int qj = 0; qj < 4; ++qj)
        accO[ti][qj] = __builtin_amdgcn_mfma_f32_16x16x32_bf16(af2[ti], bf2[qj], accO[ti][qj], 0, 0, 0);
  }

#pragma unroll
  for (int qj = 0; qj < 4; ++qj) {
    int q = 16 * qj + l15;
    if (q < 49) {
#pragma unroll
      for (int ti = 0; ti < 2; ++ti) {
        ushort4 ov;
        ov.x = f2bf(accO[ti][qj][0]);
        ov.y = f2bf(accO[ti][qj][1]);
        ov.z = f2bf(accO[ti][qj][2]);
        ov.w = f2bf(accO[ti][qj][3]);
        *(ushort4*)(o + ((size_t)lw * 49 + q) * 256 + head * 32 + 16 * ti + 4 * g) = ov;
      }
    }
  }
}

// ---------------------------------------------------------------------------
__global__ __launch_bounds__(256) void k_pool(const float* __restrict__ tok,
                                              float* __restrict__ pooled) {
  int b = blockIdx.x, c = threadIdx.x;
  float s = 0.f;
  for (int hw = 0; hw < 196; ++hw) s += tok[((size_t)b * 196 + hw) * 256 + c];
  pooled[b * 256 + c] = s * (1.f / 196.f);
}

__global__ __launch_bounds__(64) void k_head(const float* __restrict__ pooled,
                                             const float* __restrict__ w,
                                             const float* __restrict__ bias,
                                             float* __restrict__ out) {
  int b = blockIdx.x, t = threadIdx.x;
  if (t < 7) {
    float s = bias[t];
    for (int c = 0; c < 256; ++c) s = fmaf(pooled[b * 256 + c], w[c * 7 + t], s);
    out[b * 7 + t] = s;
  }
}

// ---------------------------------------------------------------------------
extern "C" void kernel_launch(void* const* d_in, const int* in_sizes, int n_in,
                              void* d_out, int out_size, void* d_ws, size_t ws_size,
                              hipStream_t stream) {
  const float* x      = (const float*)d_in[0];
  const float* conv_w = (const float*)d_in[1];
  const float* conv_b = (const float*)d_in[2];
  const float* ln1_g  = (const float*)d_in[3];
  const float* ln1_b  = (const float*)d_in[4];
  const float* qkv_w  = (const float*)d_in[5];
  const float* qkv_b  = (const float*)d_in[6];
  const float* rpb    = (const float*)d_in[7];
  const float* proj_w = (const float*)d_in[8];
  const float* proj_b = (const float*)d_in[9];
  const float* ln2_g  = (const float*)d_in[10];
  const float* ln2_b  = (const float*)d_in[11];
  const float* fc1_w  = (const float*)d_in[12];
  const float* fc1_b  = (const float*)d_in[13];
  const float* fc2_w  = (const float*)d_in[14];
  const float* fc2_b  = (const float*)d_in[15];
  const float* fco_w  = (const float*)d_in[16];
  const float* fco_b  = (const float*)d_in[17];
  float* out = (float*)d_out;
  char* p = (char*)d_ws;

  const size_t FULL_NEED = 207486976ull;
  const int nch = (ws_size >= FULL_NEED) ? 1 : 4;
  const int chw = 1024 / nch;
  const size_t chrows = (size_t)chw * 49;
  const int nMt = (int)(chrows / BM);

  float* tok = (float*)p;                     p += (size_t)MTOT * 256 * 4;
  unsigned short* Bbuf = (unsigned short*)p;  p += chrows * 1024 * 2;
  unsigned short* Abuf = (unsigned short*)p;  p += chrows * 256 * 2;
  unsigned short* Cbuf = (unsigned short*)p;  p += chrows * 256 * 2;
  unsigned short* cwB  = (unsigned short*)p;  p += 65536 * 2;
  unsigned short* qkvT = (unsigned short*)p;  p += 196608 * 2;
  unsigned short* projT= (unsigned short*)p;  p += 65536 * 2;
  unsigned short* fc1T = (unsigned short*)p;  p += 262144 * 2;
  unsigned short* fc2T = (unsigned short*)p;  p += 262144 * 2;
  float* pool = (float*)p;                    p += 65536 * 4;
  unsigned short* xt = Bbuf;

  k_cast<<<256, 256, 0, stream>>>(conv_w, cwB, 65536);
  k_wtrans<<<dim3(8, 24), 256, 0, stream>>>(qkv_w, qkvT, 256, 768);
  k_wtrans<<<dim3(8, 8), 256, 0, stream>>>(proj_w, projT, 256, 256);
  k_wtrans<<<dim3(8, 32), 256, 0, stream>>>(fc1_w, fc1T, 256, 1024);
  k_wtrans<<<dim3(32, 8), 256, 0, stream>>>(fc2_w, fc2T, 1024, 256);

  k_transpose_x<<<dim3(BATCH, 7, 8), 256, 0, stream>>>(x, xt);
  k_gemm_mfma<4><<<(MTOT / BM) * 2, 256, 0, stream>>>(xt, cwB, conv_b, tok, 0, 256, 256, MTOT / BM);

  for (int c = 0; c < nch; ++c) {
    const int rowbase = c * (int)chrows;
    k_layernorm<true><<<chrows / 4, 256, 0, stream>>>(tok, ln1_g, ln1_b, Abuf, rowbase);
    k_gemm_mfma<0><<<nMt * 6, 256, 0, stream>>>(Abuf, qkvT, qkv_b, Bbuf, 0, 768, 256, nMt);
    k_attention<<<chw * 2, 256, 0, stream>>>(Bbuf, rpb, Cbuf);
    k_gemm_mfma<2><<<nMt * 2, 256, 0, stream>>>(Cbuf, projT, proj_b, tok, rowbase, 256, 256, nMt);
    k_layernorm<false><<<chrows / 4, 256, 0, stream>>>(tok, ln2_g, ln2_b, Abuf, rowbase);
    k_gemm_mfma<1><<<nMt * 8, 256, 0, stream>>>(Abuf, fc1T, fc1_b, Bbuf, 0, 1024, 256, nMt);
    k_gemm_mfma<3><<<nMt * 2, 256, 0, stream>>>(Bbuf, fc2T, fc2_b, tok, rowbase, 256, 1024, nMt);
  }

  k_pool<<<BATCH, 256, 0, stream>>>(tok, pool);
  k_head<<<BATCH, 64, 0, stream>>>(pool, fco_w, fco_b, out);
}

// Round 9
// 356.294 us; speedup vs baseline: 5.1684x; 1.0433x over previous
//
#include <hip/hip_runtime.h>
#include <math.h>

#define NHEADS 8
#define BATCH  256
#define HWTOK  196
#define MTOT   50176          // 1024 windows * 49

#define BM 128
#define BN 128
#define BK 64

typedef short bfrag8 __attribute__((ext_vector_type(8)));
typedef float ffrag4 __attribute__((ext_vector_type(4)));

// ---------------------------------------------------------------------------
__device__ __forceinline__ unsigned short f2bf(float f) {
  union { float f; unsigned u; } v; v.f = f;
  unsigned r = v.u + 0x7fffu + ((v.u >> 16) & 1u);   // RNE
  return (unsigned short)(r >> 16);
}
__device__ __forceinline__ float bf2f(unsigned short b) {
  union { unsigned u; float f; } v; v.u = ((unsigned)b) << 16;
  return v.f;
}
// GELU exact-erf via A&S 7.1.26 poly (|err| <= 1.5e-7), one __expf + ~9 FMA
__device__ __forceinline__ float gelu_exact(float x) {
  float ax = fabsf(x) * 0.70710678118654752f;
  float t = 1.0f / (1.0f + 0.3275911f * ax);
  float y = t * (0.254829592f +
            t * (-0.284496736f +
            t * (1.421413741f +
            t * (-1.453152027f +
            t * 1.061405429f))));
  float e = 1.0f - y * __expf(-ax * ax);
  float erfv = copysignf(e, x);
  return 0.5f * x * (1.0f + erfv);
}
__device__ __forceinline__ int window_reverse_row(int m) {
  int widx = m / 49, pos = m % 49;
  int b = widx >> 2, wh = (widx >> 1) & 1, ww = widx & 1;
  int i = pos / 7, j = pos % 7;
  return b * 196 + (wh * 7 + i) * 14 + (ww * 7 + j);
}

__device__ __forceinline__ void gload16(const void* g, void* l) {
  __builtin_amdgcn_global_load_lds(
      (const __attribute__((address_space(1))) void*)g,
      (__attribute__((address_space(3))) void*)l, 16, 0, 0);
}

// ---------------------------------------------------------------------------
// bf16 MFMA GEMM: A [M][K] bf16, BT [N][K] bf16, 128x128 tile, BK=64.
// m97-exact single-buffered 2-barrier K-loop (32 KB LDS -> 5 blocks/CU; TLP
// hides staging latency), XOR-swizzled LDS (source-side pre-swizzle), grid
// m-fastest, vectorized bf16 epilogue via LDS bounce.
// LDS u16 map: A @0 (8192), B @8192 (8192); epilogue bounce uses all 16384.
// EPI 0: Cout(bf16)=acc+bias ; 1: gelu ; 2: f32 RMW window_reverse ;
// 3: f32 RMW rowbase+m ; 4: f32 store
template <int EPI>
__global__ __launch_bounds__(256) void k_gemm_mfma(const unsigned short* __restrict__ A,
                                                   const unsigned short* __restrict__ BT,
                                                   const float* __restrict__ bias,
                                                   void* __restrict__ Cout,
                                                   int rowbase, int N, int K, int nMt) {
  __shared__ __align__(128) unsigned short S[16384];   // 32 KB
  const int t = threadIdx.x;
  const int lane = t & 63, w = t >> 6;
  const int wr = w >> 1, wc = w & 1;
  const int m_t = blockIdx.x % nMt, n_t = blockIdx.x / nMt;
  const int m0 = m_t * BM, n0 = n_t * BN;
  const int l15 = lane & 15;
  const int sw = (lane & 7) << 3;                 // read-side XOR (elements)
  const int rA = lane >> 3;                       // staging row within segment
  const int kin = (((lane & 7) ^ rA) << 3);       // swizzled source col (elems)
  ffrag4 acc[4][4] = {};

  for (int k0 = 0; k0 < K; k0 += BK) {
    // stage A-tile @byte 0, B-tile @byte 16384
#pragma unroll
    for (int i = 0; i < 4; ++i) {
      const int seg = i * 4 + w;                  // wave-uniform 0..15
      const int row = seg * 8 + rA;               // 0..127
      gload16(A + (size_t)(m0 + row) * K + k0 + kin, (char*)S + seg * 1024);
      gload16(BT + (size_t)(n0 + row) * K + k0 + kin, (char*)S + 16384 + seg * 1024);
    }
    __syncthreads();   // staging complete (compiler drains vmcnt)
#pragma unroll
    for (int kk = 0; kk < BK; kk += 32) {
      bfrag8 af[4], bfr[4];
      const int colA = (kk + (lane >> 4) * 8) ^ sw;
#pragma unroll
      for (int mi = 0; mi < 4; ++mi) {
        int row = wr * 64 + mi * 16 + l15;
        af[mi] = *(const bfrag8*)&S[row * BK + colA];
      }
#pragma unroll
      for (int ni = 0; ni < 4; ++ni) {
        int col = wc * 64 + ni * 16 + l15;
        bfr[ni] = *(const bfrag8*)&S[8192 + col * BK + colA];
      }
#pragma unroll
      for (int mi = 0; mi < 4; ++mi)
#pragma unroll
        for (int ni = 0; ni < 4; ++ni)
          acc[mi][ni] = __builtin_amdgcn_mfma_f32_16x16x32_bf16(af[mi], bfr[ni], acc[mi][ni], 0, 0, 0);
    }
    __syncthreads();   // compute done before next stage overwrites
  }

  const int cr = (lane >> 4) * 4;
  const int cc = l15;
  float bv[4];
#pragma unroll
  for (int ni = 0; ni < 4; ++ni) bv[ni] = bias[n0 + wc * 64 + ni * 16 + cc];

  if (EPI == 0 || EPI == 1) {
    // bounce through LDS for vectorized 16B stores (last barrier already done)
#pragma unroll
    for (int mi = 0; mi < 4; ++mi) {
#pragma unroll
      for (int j = 0; j < 4; ++j) {
        const int ml = wr * 64 + mi * 16 + cr + j;
#pragma unroll
        for (int ni = 0; ni < 4; ++ni) {
          const int nl = wc * 64 + ni * 16 + cc;
          float v = acc[mi][ni][j] + bv[ni];
          if (EPI == 1) v = gelu_exact(v);
          S[ml * 128 + nl] = f2bf(v);
        }
      }
    }
    __syncthreads();
#pragma unroll
    for (int r = 0; r < 8; ++r) {
      const int flat = (r * 256 + t) * 8;          // u16 elements
      const int ml = flat >> 7, nl = flat & 127;
      uint4 vv = *(const uint4*)&S[flat];
      *(uint4*)((unsigned short*)Cout + (size_t)(m0 + ml) * N + n0 + nl) = vv;
    }
  } else {
#pragma unroll
    for (int mi = 0; mi < 4; ++mi) {
#pragma unroll
      for (int j = 0; j < 4; ++j) {
        const int m = m0 + wr * 64 + mi * 16 + cr + j;
        int row;
        if (EPI == 2) row = window_reverse_row(rowbase + m);
        else if (EPI == 3) row = rowbase + m;
        else row = m;
#pragma unroll
        for (int ni = 0; ni < 4; ++ni) {
          const int n = n0 + wc * 64 + ni * 16 + cc;
          float v = acc[mi][ni][j] + bv[ni];
          if (EPI == 4) {
            ((float*)Cout)[(size_t)row * N + n] = v;
          } else {
            float* p = (float*)Cout + (size_t)row * N + n;
            *p += v;
          }
        }
      }
    }
  }
}

// ---------------------------------------------------------------------------
__global__ __launch_bounds__(256) void k_wtrans(const float* __restrict__ w,
                                                unsigned short* __restrict__ wt,
                                                int K, int N) {
  __shared__ float tile[32][33];
  int k0 = blockIdx.x * 32, n0 = blockIdx.y * 32;
  int tx = threadIdx.x & 31, ty = threadIdx.x >> 5;
#pragma unroll
  for (int r = 0; r < 4; ++r)
    tile[ty + r * 8][tx] = w[(size_t)(k0 + ty + r * 8) * N + n0 + tx];
  __syncthreads();
#pragma unroll
  for (int r = 0; r < 4; ++r)
    wt[(size_t)(n0 + ty + r * 8) * K + k0 + tx] = f2bf(tile[tx][ty + r * 8]);
}

__global__ __launch_bounds__(256) void k_cast(const float* __restrict__ w,
                                              unsigned short* __restrict__ wb, int n) {
  int i = blockIdx.x * 256 + threadIdx.x;
  if (i < n) wb[i] = f2bf(w[i]);
}

__global__ __launch_bounds__(256) void k_transpose_x(const float* __restrict__ x,
                                                     unsigned short* __restrict__ xt) {
  __shared__ float tile[32][33];
  int b = blockIdx.x;
  int hw0 = blockIdx.y * 32;
  int c0 = blockIdx.z * 32;
  int tx = threadIdx.x & 31, ty = threadIdx.x >> 5;
#pragma unroll
  for (int r = 0; r < 4; ++r) {
    int c = c0 + ty + r * 8, hw = hw0 + tx;
    if (hw < HWTOK) tile[ty + r * 8][tx] = x[((size_t)b * 256 + c) * HWTOK + hw];
  }
  __syncthreads();
#pragma unroll
  for (int r = 0; r < 4; ++r) {
    int hw = hw0 + ty + r * 8, c = c0 + tx;
    if (hw < HWTOK) xt[((size_t)b * HWTOK + hw) * 256 + c] = f2bf(tile[tx][ty + r * 8]);
  }
}

// ---------------------------------------------------------------------------
template <bool WINDOW>
__global__ __launch_bounds__(256) void k_layernorm(const float* __restrict__ in,
                                                   const float* __restrict__ g,
                                                   const float* __restrict__ bta,
                                                   unsigned short* __restrict__ out,
                                                   int rowbase) {
  int wid = threadIdx.x >> 6, lane = threadIdx.x & 63;
  int li = blockIdx.x * 4 + wid;
  int token = rowbase + li;
  const float4 xv = *(const float4*)(in + (size_t)token * 256 + lane * 4);
  float s = xv.x + xv.y + xv.z + xv.w;
  float sq = xv.x * xv.x + xv.y * xv.y + xv.z * xv.z + xv.w * xv.w;
#pragma unroll
  for (int off = 32; off >= 1; off >>= 1) {
    s += __shfl_xor(s, off);
    sq += __shfl_xor(sq, off);
  }
  float mean = s * (1.f / 256.f);
  float var = sq * (1.f / 256.f) - mean * mean;
  float rstd = rsqrtf(var + 1e-5f);
  float4 gv = *(const float4*)(g + lane * 4);
  float4 bv = *(const float4*)(bta + lane * 4);
  ushort4 ov;
  ov.x = f2bf((xv.x - mean) * rstd * gv.x + bv.x);
  ov.y = f2bf((xv.y - mean) * rstd * gv.y + bv.y);
  ov.z = f2bf((xv.z - mean) * rstd * gv.z + bv.z);
  ov.w = f2bf((xv.w - mean) * rstd * gv.w + bv.w);
  int orow;
  if (WINDOW) {
    int b = token / 196, hw = token % 196;
    int h14 = hw / 14, w14 = hw % 14;
    int wh = h14 / 7, i = h14 % 7, ww = w14 / 7, j = w14 % 7;
    int widx = (b * 2 + wh) * 2 + ww;
    orow = widx * 49 + i * 7 + j - rowbase;
  } else {
    orow = li;
  }
  *(ushort4*)(out + (size_t)orow * 256 + lane * 4) = ov;
}

// ---------------------------------------------------------------------------
// MFMA attention: one WAVE per (window, head); 4 independent waves per block.
__global__ __launch_bounds__(256) void k_attention(const unsigned short* __restrict__ qkv,
                                                   const float* __restrict__ rpb,
                                                   unsigned short* __restrict__ o) {
  __shared__ unsigned short Kl[4][64 * 40];
  __shared__ unsigned short VTl[4][32 * 72];
  __shared__ unsigned short Pl[4][64 * 72];
  __shared__ float rpbl[4][176];

  const int t = threadIdx.x;
  const int w4 = t >> 6, lane = t & 63;
  const int l15 = lane & 15, g = lane >> 4;
  const int gw = blockIdx.x * 4 + w4;
  const int lw = gw >> 3, head = gw & 7;

  unsigned short* K_ = Kl[w4];
  unsigned short* VT_ = VTl[w4];
  unsigned short* P_ = Pl[w4];
  float* rpb_ = rpbl[w4];

  const size_t baseq = (size_t)lw * 49 * 768 + head * 32;

  for (int e = lane; e < 169; e += 64) rpb_[e] = rpb[e * 8 + head];

  for (int e = lane; e < 512; e += 64) {
    int d = e >> 4, tk = 48 + (e & 15);
    if ((e & 15) != 0) VT_[d * 72 + tk] = 0;
  }

  for (int e = lane; e < 784; e += 64) {
    int tok = e >> 4, dp = e & 15;
    unsigned kv = *(const unsigned*)(qkv + baseq + 256 + (size_t)tok * 768 + dp * 2);
    *(unsigned*)&K_[tok * 40 + dp * 2] = kv;
    unsigned vv = *(const unsigned*)(qkv + baseq + 512 + (size_t)tok * 768 + dp * 2);
    VT_[(dp * 2 + 0) * 72 + tok] = (unsigned short)(vv & 0xffffu);
    VT_[(dp * 2 + 1) * 72 + tok] = (unsigned short)(vv >> 16);
  }

  ffrag4 acc[4][4] = {};
  {
    bfrag8 af[4], bfr[4];
#pragma unroll
    for (int qi = 0; qi < 4; ++qi)
      af[qi] = *(const bfrag8*)(qkv + baseq + (size_t)(16 * qi + l15) * 768 + g * 8);
#pragma unroll
    for (int kj = 0; kj < 4; ++kj)
      bfr[kj] = *(const bfrag8*)&K_[(16 * kj + l15) * 40 + g * 8];
#pragma unroll
    for (int qi = 0; qi < 4; ++qi)
#pragma unroll
      for (int kj = 0; kj < 4; ++kj)
        acc[qi][kj] = __builtin_amdgcn_mfma_f32_16x16x32_bf16(af[qi], bfr[kj], acc[qi][kj], 0, 0, 0);
  }

  const float scale = 0.17677669529663687f;
  int kc[4];
  bool kvalid[4];
#pragma unroll
  for (int kj = 0; kj < 4; ++kj) {
    int c = 16 * kj + l15;
    kc[kj] = 13 * (c / 7) + (c % 7);
    kvalid[kj] = (c < 49);
  }
#pragma unroll
  for (int qi = 0; qi < 4; ++qi) {
#pragma unroll
    for (int j = 0; j < 4; ++j) {
      int q = 16 * qi + 4 * g + j;
      int qc = 13 * (q / 7) + (q % 7);
      float tv[4];
#pragma unroll
      for (int kj = 0; kj < 4; ++kj)
        tv[kj] = kvalid[kj] ? (acc[qi][kj][j] * scale + rpb_[qc - kc[kj] + 84]) : -INFINITY;
      float mx = fmaxf(fmaxf(tv[0], tv[1]), fmaxf(tv[2], tv[3]));
#pragma unroll
      for (int off = 8; off >= 1; off >>= 1) mx = fmaxf(mx, __shfl_xor(mx, off));
      float p[4], sum = 0.f;
#pragma unroll
      for (int kj = 0; kj < 4; ++kj) {
        p[kj] = kvalid[kj] ? __expf(tv[kj] - mx) : 0.f;
        sum += p[kj];
      }
#pragma unroll
      for (int off = 8; off >= 1; off >>= 1) sum += __shfl_xor(sum, off);
      float inv = 1.0f / sum;
      if (q < 49) {
#pragma unroll
        for (int kj = 0; kj < 4; ++kj)
          P_[q * 72 + 16 * kj + l15] = f2bf(p[kj] * inv);
      }
    }
  }

  ffrag4 accO[2][4] = {};
#pragma unroll
  for (int kk = 0; kk < 64; kk += 32) {
    bfrag8 af2[2], bf2[4];
#pragma unroll
    for (int ti = 0; ti < 2; ++ti)
      af2[ti] = *(const bfrag8*)&VT_[(16 * ti + l15) * 72 + kk + g * 8];
#pragma unroll
    for (int qj = 0; qj < 4; ++qj)
      bf2[qj] = *(const bfrag8*)&P_[(16 * qj + l15) * 72 + kk + g * 8];
#pragma unroll
    for (int ti = 0; ti < 2; ++ti)
#pragma unroll
      for (int qj = 0; qj < 4; ++qj)
        accO[ti][qj] = __builtin_amdgcn_mfma_f32_16x16x32_bf16(af2[ti], bf2[qj], accO[ti][qj], 0, 0, 0);
  }

#pragma unroll
  for (int qj = 0; qj < 4; ++qj) {
    int q = 16 * qj + l15;
    if (q < 49) {
#pragma unroll
      for (int ti = 0; ti < 2; ++ti) {
        ushort4 ov;
        ov.x = f2bf(accO[ti][qj][0]);
        ov.y = f2bf(accO[ti][qj][1]);
        ov.z = f2bf(accO[ti][qj][2]);
        ov.w = f2bf(accO[ti][qj][3]);
        *(ushort4*)(o + ((size_t)lw * 49 + q) * 256 + head * 32 + 16 * ti + 4 * g) = ov;
      }
    }
  }
}

// ---------------------------------------------------------------------------
__global__ __launch_bounds__(256) void k_pool(const float* __restrict__ tok,
                                              float* __restrict__ pooled) {
  int b = blockIdx.x, c = threadIdx.x;
  float s = 0.f;
  for (int hw = 0; hw < 196; ++hw) s += tok[((size_t)b * 196 + hw) * 256 + c];
  pooled[b * 256 + c] = s * (1.f / 196.f);
}

__global__ __launch_bounds__(64) void k_head(const float* __restrict__ pooled,
                                             const float* __restrict__ w,
                                             const float* __restrict__ bias,
                                             float* __restrict__ out) {
  int b = blockIdx.x, t = threadIdx.x;
  if (t < 7) {
    float s = bias[t];
    for (int c = 0; c < 256; ++c) s = fmaf(pooled[b * 256 + c], w[c * 7 + t], s);
    out[b * 7 + t] = s;
  }
}

// ---------------------------------------------------------------------------
extern "C" void kernel_launch(void* const* d_in, const int* in_sizes, int n_in,
                              void* d_out, int out_size, void* d_ws, size_t ws_size,
                              hipStream_t stream) {
  const float* x      = (const float*)d_in[0];
  const float* conv_w = (const float*)d_in[1];
  const float* conv_b = (const float*)d_in[2];
  const float* ln1_g  = (const float*)d_in[3];
  const float* ln1_b  = (const float*)d_in[4];
  const float* qkv_w  = (const float*)d_in[5];
  const float* qkv_b  = (const float*)d_in[6];
  const float* rpb    = (const float*)d_in[7];
  const float* proj_w = (const float*)d_in[8];
  const float* proj_b = (const float*)d_in[9];
  const float* ln2_g  = (const float*)d_in[10];
  const float* ln2_b  = (const float*)d_in[11];
  const float* fc1_w  = (const float*)d_in[12];
  const float* fc1_b  = (const float*)d_in[13];
  const float* fc2_w  = (const float*)d_in[14];
  const float* fc2_b  = (const float*)d_in[15];
  const float* fco_w  = (const float*)d_in[16];
  const float* fco_b  = (const float*)d_in[17];
  float* out = (float*)d_out;
  char* p = (char*)d_ws;

  const size_t FULL_NEED = 207486976ull;
  const int nch = (ws_size >= FULL_NEED) ? 1 : 4;
  const int chw = 1024 / nch;
  const size_t chrows = (size_t)chw * 49;
  const int nMt = (int)(chrows / BM);

  float* tok = (float*)p;                     p += (size_t)MTOT * 256 * 4;
  unsigned short* Bbuf = (unsigned short*)p;  p += chrows * 1024 * 2;
  unsigned short* Abuf = (unsigned short*)p;  p += chrows * 256 * 2;
  unsigned short* Cbuf = (unsigned short*)p;  p += chrows * 256 * 2;
  unsigned short* cwB  = (unsigned short*)p;  p += 65536 * 2;
  unsigned short* qkvT = (unsigned short*)p;  p += 196608 * 2;
  unsigned short* projT= (unsigned short*)p;  p += 65536 * 2;
  unsigned short* fc1T = (unsigned short*)p;  p += 262144 * 2;
  unsigned short* fc2T = (unsigned short*)p;  p += 262144 * 2;
  float* pool = (float*)p;                    p += 65536 * 4;
  unsigned short* xt = Bbuf;

  k_cast<<<256, 256, 0, stream>>>(conv_w, cwB, 65536);
  k_wtrans<<<dim3(8, 24), 256, 0, stream>>>(qkv_w, qkvT, 256, 768);
  k_wtrans<<<dim3(8, 8), 256, 0, stream>>>(proj_w, projT, 256, 256);
  k_wtrans<<<dim3(8, 32), 256, 0, stream>>>(fc1_w, fc1T, 256, 1024);
  k_wtrans<<<dim3(32, 8), 256, 0, stream>>>(fc2_w, fc2T, 1024, 256);

  k_transpose_x<<<dim3(BATCH, 7, 8), 256, 0, stream>>>(x, xt);
  k_gemm_mfma<4><<<(MTOT / BM) * 2, 256, 0, stream>>>(xt, cwB, conv_b, tok, 0, 256, 256, MTOT / BM);

  for (int c = 0; c < nch; ++c) {
    const int rowbase = c * (int)chrows;
    k_layernorm<true><<<chrows / 4, 256, 0, stream>>>(tok, ln1_g, ln1_b, Abuf, rowbase);
    k_gemm_mfma<0><<<nMt * 6, 256, 0, stream>>>(Abuf, qkvT, qkv_b, Bbuf, 0, 768, 256, nMt);
    k_attention<<<chw * 2, 256, 0, stream>>>(Bbuf, rpb, Cbuf);
    k_gemm_mfma<2><<<nMt * 2, 256, 0, stream>>>(Cbuf, projT, proj_b, tok, rowbase, 256, 256, nMt);
    k_layernorm<false><<<chrows / 4, 256, 0, stream>>>(tok, ln2_g, ln2_b, Abuf, rowbase);
    k_gemm_mfma<1><<<nMt * 8, 256, 0, stream>>>(Abuf, fc1T, fc1_b, Bbuf, 0, 1024, 256, nMt);
    k_gemm_mfma<3><<<nMt * 2, 256, 0, stream>>>(Bbuf, fc2T, fc2_b, tok, rowbase, 256, 1024, nMt);
  }

  k_pool<<<BATCH, 256, 0, stream>>>(tok, pool);
  k_head<<<BATCH, 64, 0, stream>>>(pool, fco_w, fco_b, out);
}

// Round 10
// 344.792 us; speedup vs baseline: 5.3408x; 1.0334x over previous
//
#include <hip/hip_runtime.h>
#include <math.h>

#define NHEADS 8
#define BATCH  256
#define HWTOK  196
#define MTOT   50176          // 1024 windows * 49

#define BM 128
#define BN 128
#define BK 64

typedef short bfrag8 __attribute__((ext_vector_type(8)));
typedef float ffrag4 __attribute__((ext_vector_type(4)));

// ---------------------------------------------------------------------------
__device__ __forceinline__ unsigned short f2bf(float f) {
  union { float f; unsigned u; } v; v.f = f;
  unsigned r = v.u + 0x7fffu + ((v.u >> 16) & 1u);   // RNE
  return (unsigned short)(r >> 16);
}
__device__ __forceinline__ float bf2f(unsigned short b) {
  union { unsigned u; float f; } v; v.u = ((unsigned)b) << 16;
  return v.f;
}
// GELU exact-erf via A&S 7.1.26 poly (|err| <= 1.5e-7), one __expf + ~9 FMA
__device__ __forceinline__ float gelu_exact(float x) {
  float ax = fabsf(x) * 0.70710678118654752f;
  float t = 1.0f / (1.0f + 0.3275911f * ax);
  float y = t * (0.254829592f +
            t * (-0.284496736f +
            t * (1.421413741f +
            t * (-1.453152027f +
            t * 1.061405429f))));
  float e = 1.0f - y * __expf(-ax * ax);
  float erfv = copysignf(e, x);
  return 0.5f * x * (1.0f + erfv);
}
__device__ __forceinline__ int window_reverse_row(int m) {
  int widx = m / 49, pos = m % 49;
  int b = widx >> 2, wh = (widx >> 1) & 1, ww = widx & 1;
  int i = pos / 7, j = pos % 7;
  return b * 196 + (wh * 7 + i) * 14 + (ww * 7 + j);
}

__device__ __forceinline__ void gload16(const void* g, void* l) {
  __builtin_amdgcn_global_load_lds(
      (const __attribute__((address_space(1))) void*)g,
      (__attribute__((address_space(3))) void*)l, 16, 0, 0);
}

// ---------------------------------------------------------------------------
// bf16 MFMA GEMM: A [M][K] bf16, BT [N][K] bf16, 128x128 tile, BK=64.
// Single-buffered m97 2-barrier K-loop, XOR-swizzled LDS, XCD-chunked block
// swizzle + n-fastest tile order (per-XCD A working set 3.1 MB -> L2-resident,
// weights L2-resident, A fetched ~once from HBM), vectorized bf16 epilogue.
// EPI 0: Cout(bf16)=acc+bias ; 1: gelu ; 2: f32 RMW window_reverse ;
// 3: f32 RMW rowbase+m ; 4: f32 store
template <int EPI>
__global__ __launch_bounds__(256) void k_gemm_mfma(const unsigned short* __restrict__ A,
                                                   const unsigned short* __restrict__ BT,
                                                   const float* __restrict__ bias,
                                                   void* __restrict__ Cout,
                                                   int rowbase, int N, int K, int nNt) {
  __shared__ __align__(128) unsigned short S[16384];   // 32 KB
  const int t = threadIdx.x;
  const int lane = t & 63, w = t >> 6;
  const int wr = w >> 1, wc = w & 1;
  // XCD-chunked swizzle (grid % 8 == 0 for all our launches): XCD x owns a
  // contiguous logical range; n-fastest => same A-tile reused across n_t.
  const int cpx = gridDim.x >> 3;
  const int lb = (blockIdx.x & 7) * cpx + (blockIdx.x >> 3);
  const int n_t = lb % nNt, m_t = lb / nNt;
  const int m0 = m_t * BM, n0 = n_t * BN;
  const int l15 = lane & 15;
  const int sw = (lane & 7) << 3;                 // read-side XOR (elements)
  const int rA = lane >> 3;                       // staging row within segment
  const int kin = (((lane & 7) ^ rA) << 3);       // swizzled source col (elems)
  ffrag4 acc[4][4] = {};

  for (int k0 = 0; k0 < K; k0 += BK) {
    // stage A-tile @byte 0, B-tile @byte 16384
#pragma unroll
    for (int i = 0; i < 4; ++i) {
      const int seg = i * 4 + w;                  // wave-uniform 0..15
      const int row = seg * 8 + rA;               // 0..127
      gload16(A + (size_t)(m0 + row) * K + k0 + kin, (char*)S + seg * 1024);
      gload16(BT + (size_t)(n0 + row) * K + k0 + kin, (char*)S + 16384 + seg * 1024);
    }
    __syncthreads();   // staging complete (compiler drains vmcnt)
#pragma unroll
    for (int kk = 0; kk < BK; kk += 32) {
      bfrag8 af[4], bfr[4];
      const int colA = (kk + (lane >> 4) * 8) ^ sw;
#pragma unroll
      for (int mi = 0; mi < 4; ++mi) {
        int row = wr * 64 + mi * 16 + l15;
        af[mi] = *(const bfrag8*)&S[row * BK + colA];
      }
#pragma unroll
      for (int ni = 0; ni < 4; ++ni) {
        int col = wc * 64 + ni * 16 + l15;
        bfr[ni] = *(const bfrag8*)&S[8192 + col * BK + colA];
      }
#pragma unroll
      for (int mi = 0; mi < 4; ++mi)
#pragma unroll
        for (int ni = 0; ni < 4; ++ni)
          acc[mi][ni] = __builtin_amdgcn_mfma_f32_16x16x32_bf16(af[mi], bfr[ni], acc[mi][ni], 0, 0, 0);
    }
    __syncthreads();   // compute done before next stage overwrites
  }

  const int cr = (lane >> 4) * 4;
  const int cc = l15;
  float bv[4];
#pragma unroll
  for (int ni = 0; ni < 4; ++ni) bv[ni] = bias[n0 + wc * 64 + ni * 16 + cc];

  if (EPI == 0 || EPI == 1) {
    // bounce through LDS for vectorized 16B stores (last barrier already done)
#pragma unroll
    for (int mi = 0; mi < 4; ++mi) {
#pragma unroll
      for (int j = 0; j < 4; ++j) {
        const int ml = wr * 64 + mi * 16 + cr + j;
#pragma unroll
        for (int ni = 0; ni < 4; ++ni) {
          const int nl = wc * 64 + ni * 16 + cc;
          float v = acc[mi][ni][j] + bv[ni];
          if (EPI == 1) v = gelu_exact(v);
          S[ml * 128 + nl] = f2bf(v);
        }
      }
    }
    __syncthreads();
#pragma unroll
    for (int r = 0; r < 8; ++r) {
      const int flat = (r * 256 + t) * 8;          // u16 elements
      const int ml = flat >> 7, nl = flat & 127;
      uint4 vv = *(const uint4*)&S[flat];
      *(uint4*)((unsigned short*)Cout + (size_t)(m0 + ml) * N + n0 + nl) = vv;
    }
  } else {
#pragma unroll
    for (int mi = 0; mi < 4; ++mi) {
#pragma unroll
      for (int j = 0; j < 4; ++j) {
        const int m = m0 + wr * 64 + mi * 16 + cr + j;
        int row;
        if (EPI == 2) row = window_reverse_row(rowbase + m);
        else if (EPI == 3) row = rowbase + m;
        else row = m;
#pragma unroll
        for (int ni = 0; ni < 4; ++ni) {
          const int n = n0 + wc * 64 + ni * 16 + cc;
          float v = acc[mi][ni][j] + bv[ni];
          if (EPI == 4) {
            ((float*)Cout)[(size_t)row * N + n] = v;
          } else {
            float* p = (float*)Cout + (size_t)row * N + n;
            *p += v;
          }
        }
      }
    }
  }
}

// ---------------------------------------------------------------------------
__global__ __launch_bounds__(256) void k_wtrans(const float* __restrict__ w,
                                                unsigned short* __restrict__ wt,
                                                int K, int N) {
  __shared__ float tile[32][33];
  int k0 = blockIdx.x * 32, n0 = blockIdx.y * 32;
  int tx = threadIdx.x & 31, ty = threadIdx.x >> 5;
#pragma unroll
  for (int r = 0; r < 4; ++r)
    tile[ty + r * 8][tx] = w[(size_t)(k0 + ty + r * 8) * N + n0 + tx];
  __syncthreads();
#pragma unroll
  for (int r = 0; r < 4; ++r)
    wt[(size_t)(n0 + ty + r * 8) * K + k0 + tx] = f2bf(tile[tx][ty + r * 8]);
}

__global__ __launch_bounds__(256) void k_cast(const float* __restrict__ w,
                                              unsigned short* __restrict__ wb, int n) {
  int i = blockIdx.x * 256 + threadIdx.x;
  if (i < n) wb[i] = f2bf(w[i]);
}

__global__ __launch_bounds__(256) void k_transpose_x(const float* __restrict__ x,
                                                     unsigned short* __restrict__ xt) {
  __shared__ float tile[32][33];
  int b = blockIdx.x;
  int hw0 = blockIdx.y * 32;
  int c0 = blockIdx.z * 32;
  int tx = threadIdx.x & 31, ty = threadIdx.x >> 5;
#pragma unroll
  for (int r = 0; r < 4; ++r) {
    int c = c0 + ty + r * 8, hw = hw0 + tx;
    if (hw < HWTOK) tile[ty + r * 8][tx] = x[((size_t)b * 256 + c) * HWTOK + hw];
  }
  __syncthreads();
#pragma unroll
  for (int r = 0; r < 4; ++r) {
    int hw = hw0 + ty + r * 8, c = c0 + tx;
    if (hw < HWTOK) xt[((size_t)b * HWTOK + hw) * 256 + c] = f2bf(tile[tx][ty + r * 8]);
  }
}

// ---------------------------------------------------------------------------
template <bool WINDOW>
__global__ __launch_bounds__(256) void k_layernorm(const float* __restrict__ in,
                                                   const float* __restrict__ g,
                                                   const float* __restrict__ bta,
                                                   unsigned short* __restrict__ out,
                                                   int rowbase) {
  int wid = threadIdx.x >> 6, lane = threadIdx.x & 63;
  int li = blockIdx.x * 4 + wid;
  int token = rowbase + li;
  const float4 xv = *(const float4*)(in + (size_t)token * 256 + lane * 4);
  float s = xv.x + xv.y + xv.z + xv.w;
  float sq = xv.x * xv.x + xv.y * xv.y + xv.z * xv.z + xv.w * xv.w;
#pragma unroll
  for (int off = 32; off >= 1; off >>= 1) {
    s += __shfl_xor(s, off);
    sq += __shfl_xor(sq, off);
  }
  float mean = s * (1.f / 256.f);
  float var = sq * (1.f / 256.f) - mean * mean;
  float rstd = rsqrtf(var + 1e-5f);
  float4 gv = *(const float4*)(g + lane * 4);
  float4 bv = *(const float4*)(bta + lane * 4);
  ushort4 ov;
  ov.x = f2bf((xv.x - mean) * rstd * gv.x + bv.x);
  ov.y = f2bf((xv.y - mean) * rstd * gv.y + bv.y);
  ov.z = f2bf((xv.z - mean) * rstd * gv.z + bv.z);
  ov.w = f2bf((xv.w - mean) * rstd * gv.w + bv.w);
  int orow;
  if (WINDOW) {
    int b = token / 196, hw = token % 196;
    int h14 = hw / 14, w14 = hw % 14;
    int wh = h14 / 7, i = h14 % 7, ww = w14 / 7, j = w14 % 7;
    int widx = (b * 2 + wh) * 2 + ww;
    orow = widx * 49 + i * 7 + j - rowbase;
  } else {
    orow = li;
  }
  *(ushort4*)(out + (size_t)orow * 256 + lane * 4) = ov;
}

// ---------------------------------------------------------------------------
// MFMA attention: one WAVE per (window, head); 4 independent waves per block.
__global__ __launch_bounds__(256) void k_attention(const unsigned short* __restrict__ qkv,
                                                   const float* __restrict__ rpb,
                                                   unsigned short* __restrict__ o) {
  __shared__ unsigned short Kl[4][64 * 40];
  __shared__ unsigned short VTl[4][32 * 72];
  __shared__ unsigned short Pl[4][64 * 72];
  __shared__ float rpbl[4][176];

  const int t = threadIdx.x;
  const int w4 = t >> 6, lane = t & 63;
  const int l15 = lane & 15, g = lane >> 4;
  const int gw = blockIdx.x * 4 + w4;
  const int lw = gw >> 3, head = gw & 7;

  unsigned short* K_ = Kl[w4];
  unsigned short* VT_ = VTl[w4];
  unsigned short* P_ = Pl[w4];
  float* rpb_ = rpbl[w4];

  const size_t baseq = (size_t)lw * 49 * 768 + head * 32;

  for (int e = lane; e < 169; e += 64) rpb_[e] = rpb[e * 8 + head];

  for (int e = lane; e < 512; e += 64) {
    int d = e >> 4, tk = 48 + (e & 15);
    if ((e & 15) != 0) VT_[d * 72 + tk] = 0;
  }

  for (int e = lane; e < 784; e += 64) {
    int tok = e >> 4, dp = e & 15;
    unsigned kv = *(const unsigned*)(qkv + baseq + 256 + (size_t)tok * 768 + dp * 2);
    *(unsigned*)&K_[tok * 40 + dp * 2] = kv;
    unsigned vv = *(const unsigned*)(qkv + baseq + 512 + (size_t)tok * 768 + dp * 2);
    VT_[(dp * 2 + 0) * 72 + tok] = (unsigned short)(vv & 0xffffu);
    VT_[(dp * 2 + 1) * 72 + tok] = (unsigned short)(vv >> 16);
  }

  ffrag4 acc[4][4] = {};
  {
    bfrag8 af[4], bfr[4];
#pragma unroll
    for (int qi = 0; qi < 4; ++qi)
      af[qi] = *(const bfrag8*)(qkv + baseq + (size_t)(16 * qi + l15) * 768 + g * 8);
#pragma unroll
    for (int kj = 0; kj < 4; ++kj)
      bfr[kj] = *(const bfrag8*)&K_[(16 * kj + l15) * 40 + g * 8];
#pragma unroll
    for (int qi = 0; qi < 4; ++qi)
#pragma unroll
      for (int kj = 0; kj < 4; ++kj)
        acc[qi][kj] = __builtin_amdgcn_mfma_f32_16x16x32_bf16(af[qi], bfr[kj], acc[qi][kj], 0, 0, 0);
  }

  const float scale = 0.17677669529663687f;
  int kc[4];
  bool kvalid[4];
#pragma unroll
  for (int kj = 0; kj < 4; ++kj) {
    int c = 16 * kj + l15;
    kc[kj] = 13 * (c / 7) + (c % 7);
    kvalid[kj] = (c < 49);
  }
#pragma unroll
  for (int qi = 0; qi < 4; ++qi) {
#pragma unroll
    for (int j = 0; j < 4; ++j) {
      int q = 16 * qi + 4 * g + j;
      int qc = 13 * (q / 7) + (q % 7);
      float tv[4];
#pragma unroll
      for (int kj = 0; kj < 4; ++kj)
        tv[kj] = kvalid[kj] ? (acc[qi][kj][j] * scale + rpb_[qc - kc[kj] + 84]) : -INFINITY;
      float mx = fmaxf(fmaxf(tv[0], tv[1]), fmaxf(tv[2], tv[3]));
#pragma unroll
      for (int off = 8; off >= 1; off >>= 1) mx = fmaxf(mx, __shfl_xor(mx, off));
      float p[4], sum = 0.f;
#pragma unroll
      for (int kj = 0; kj < 4; ++kj) {
        p[kj] = kvalid[kj] ? __expf(tv[kj] - mx) : 0.f;
        sum += p[kj];
      }
#pragma unroll
      for (int off = 8; off >= 1; off >>= 1) sum += __shfl_xor(sum, off);
      float inv = 1.0f / sum;
      if (q < 49) {
#pragma unroll
        for (int kj = 0; kj < 4; ++kj)
          P_[q * 72 + 16 * kj + l15] = f2bf(p[kj] * inv);
      }
    }
  }

  ffrag4 accO[2][4] = {};
#pragma unroll
  for (int kk = 0; kk < 64; kk += 32) {
    bfrag8 af2[2], bf2[4];
#pragma unroll
    for (int ti = 0; ti < 2; ++ti)
      af2[ti] = *(const bfrag8*)&VT_[(16 * ti + l15) * 72 + kk + g * 8];
#pragma unroll
    for (int qj = 0; qj < 4; ++qj)
      bf2[qj] = *(const bfrag8*)&P_[(16 * qj + l15) * 72 + kk + g * 8];
#pragma unroll
    for (int ti = 0; ti < 2; ++ti)
#pragma unroll
      for (int qj = 0; qj < 4; ++qj)
        accO[ti][qj] = __builtin_amdgcn_mfma_f32_16x16x32_bf16(af2[ti], bf2[qj], accO[ti][qj], 0, 0, 0);
  }

#pragma unroll
  for (int qj = 0; qj < 4; ++qj) {
    int q = 16 * qj + l15;
    if (q < 49) {
#pragma unroll
      for (int ti = 0; ti < 2; ++ti) {
        ushort4 ov;
        ov.x = f2bf(accO[ti][qj][0]);
        ov.y = f2bf(accO[ti][qj][1]);
        ov.z = f2bf(accO[ti][qj][2]);
        ov.w = f2bf(accO[ti][qj][3]);
        *(ushort4*)(o + ((size_t)lw * 49 + q) * 256 + head * 32 + 16 * ti + 4 * g) = ov;
      }
    }
  }
}

// ---------------------------------------------------------------------------
__global__ __launch_bounds__(256) void k_pool(const float* __restrict__ tok,
                                              float* __restrict__ pooled) {
  int b = blockIdx.x, c = threadIdx.x;
  float s = 0.f;
  for (int hw = 0; hw < 196; ++hw) s += tok[((size_t)b * 196 + hw) * 256 + c];
  pooled[b * 256 + c] = s * (1.f / 196.f);
}

__global__ __launch_bounds__(64) void k_head(const float* __restrict__ pooled,
                                             const float* __restrict__ w,
                                             const float* __restrict__ bias,
                                             float* __restrict__ out) {
  int b = blockIdx.x, t = threadIdx.x;
  if (t < 7) {
    float s = bias[t];
    for (int c = 0; c < 256; ++c) s = fmaf(pooled[b * 256 + c], w[c * 7 + t], s);
    out[b * 7 + t] = s;
  }
}

// ---------------------------------------------------------------------------
extern "C" void kernel_launch(void* const* d_in, const int* in_sizes, int n_in,
                              void* d_out, int out_size, void* d_ws, size_t ws_size,
                              hipStream_t stream) {
  const float* x      = (const float*)d_in[0];
  const float* conv_w = (const float*)d_in[1];
  const float* conv_b = (const float*)d_in[2];
  const float* ln1_g  = (const float*)d_in[3];
  const float* ln1_b  = (const float*)d_in[4];
  const float* qkv_w  = (const float*)d_in[5];
  const float* qkv_b  = (const float*)d_in[6];
  const float* rpb    = (const float*)d_in[7];
  const float* proj_w = (const float*)d_in[8];
  const float* proj_b = (const float*)d_in[9];
  const float* ln2_g  = (const float*)d_in[10];
  const float* ln2_b  = (const float*)d_in[11];
  const float* fc1_w  = (const float*)d_in[12];
  const float* fc1_b  = (const float*)d_in[13];
  const float* fc2_w  = (const float*)d_in[14];
  const float* fc2_b  = (const float*)d_in[15];
  const float* fco_w  = (const float*)d_in[16];
  const float* fco_b  = (const float*)d_in[17];
  float* out = (float*)d_out;
  char* p = (char*)d_ws;

  const size_t FULL_NEED = 207486976ull;
  const int nch = (ws_size >= FULL_NEED) ? 1 : 4;
  const int chw = 1024 / nch;
  const size_t chrows = (size_t)chw * 49;
  const int nMt = (int)(chrows / BM);

  float* tok = (float*)p;                     p += (size_t)MTOT * 256 * 4;
  unsigned short* Bbuf = (unsigned short*)p;  p += chrows * 1024 * 2;
  unsigned short* Abuf = (unsigned short*)p;  p += chrows * 256 * 2;
  unsigned short* Cbuf = (unsigned short*)p;  p += chrows * 256 * 2;
  unsigned short* cwB  = (unsigned short*)p;  p += 65536 * 2;
  unsigned short* qkvT = (unsigned short*)p;  p += 196608 * 2;
  unsigned short* projT= (unsigned short*)p;  p += 65536 * 2;
  unsigned short* fc1T = (unsigned short*)p;  p += 262144 * 2;
  unsigned short* fc2T = (unsigned short*)p;  p += 262144 * 2;
  float* pool = (float*)p;                    p += 65536 * 4;
  unsigned short* xt = Bbuf;

  k_cast<<<256, 256, 0, stream>>>(conv_w, cwB, 65536);
  k_wtrans<<<dim3(8, 24), 256, 0, stream>>>(qkv_w, qkvT, 256, 768);
  k_wtrans<<<dim3(8, 8), 256, 0, stream>>>(proj_w, projT, 256, 256);
  k_wtrans<<<dim3(8, 32), 256, 0, stream>>>(fc1_w, fc1T, 256, 1024);
  k_wtrans<<<dim3(32, 8), 256, 0, stream>>>(fc2_w, fc2T, 1024, 256);

  k_transpose_x<<<dim3(BATCH, 7, 8), 256, 0, stream>>>(x, xt);
  k_gemm_mfma<4><<<(MTOT / BM) * 2, 256, 0, stream>>>(xt, cwB, conv_b, tok, 0, 256, 256, 2);

  for (int c = 0; c < nch; ++c) {
    const int rowbase = c * (int)chrows;
    k_layernorm<true><<<chrows / 4, 256, 0, stream>>>(tok, ln1_g, ln1_b, Abuf, rowbase);
    k_gemm_mfma<0><<<nMt * 6, 256, 0, stream>>>(Abuf, qkvT, qkv_b, Bbuf, 0, 768, 256, 6);
    k_attention<<<chw * 2, 256, 0, stream>>>(Bbuf, rpb, Cbuf);
    k_gemm_mfma<2><<<nMt * 2, 256, 0, stream>>>(Cbuf, projT, proj_b, tok, rowbase, 256, 256, 2);
    k_layernorm<false><<<chrows / 4, 256, 0, stream>>>(tok, ln2_g, ln2_b, Abuf, rowbase);
    k_gemm_mfma<1><<<nMt * 8, 256, 0, stream>>>(Abuf, fc1T, fc1_b, Bbuf, 0, 1024, 256, 8);
    k_gemm_mfma<3><<<nMt * 2, 256, 0, stream>>>(Bbuf, fc2T, fc2_b, tok, rowbase, 256, 1024, 2);
  }

  k_pool<<<BATCH, 256, 0, stream>>>(tok, pool);
  k_head<<<BATCH, 64, 0, stream>>>(pool, fco_w, fco_b, out);
}

// Round 11
// 332.157 us; speedup vs baseline: 5.5440x; 1.0380x over previous
//
#include <hip/hip_runtime.h>
#include <math.h>

#define NHEADS 8
#define BATCH  256
#define HWTOK  196
#define MTOT   50176          // 1024 windows * 49

#define BM 128
#define BN 128
#define BK 64

typedef short bfrag8 __attribute__((ext_vector_type(8)));
typedef float ffrag4 __attribute__((ext_vector_type(4)));

// ---------------------------------------------------------------------------
__device__ __forceinline__ unsigned short f2bf(float f) {
  union { float f; unsigned u; } v; v.f = f;
  unsigned r = v.u + 0x7fffu + ((v.u >> 16) & 1u);   // RNE
  return (unsigned short)(r >> 16);
}
__device__ __forceinline__ float bf2f(unsigned short b) {
  union { unsigned u; float f; } v; v.u = ((unsigned)b) << 16;
  return v.f;
}
// packed bf16 convert: lo = bf16(a), hi = bf16(b), RNE
__device__ __forceinline__ unsigned cvtpk(float a, float b) {
  unsigned r;
  asm("v_cvt_pk_bf16_f32 %0, %1, %2" : "=v"(r) : "v"(a), "v"(b));
  return r;
}
// GELU exact-erf (A&S 7.1.26, |err|<=1.5e-7) with fast rcp, no copysign:
// gelu(x) = 0.5*(x + |x|*erf(|x|/sqrt2))
__device__ __forceinline__ float gelu_fast(float x) {
  float ax = fabsf(x);
  float z = ax * 0.70710678118654752f;
  float t = __builtin_amdgcn_rcpf(fmaf(z, 0.3275911f, 1.0f));
  float y = t * (0.254829592f +
            t * (-0.284496736f +
            t * (1.421413741f +
            t * (-1.453152027f +
            t * 1.061405429f))));
  float e2 = __expf(-z * z);
  float erfv = fmaf(-y, e2, 1.0f);
  return 0.5f * fmaf(ax, erfv, x);
}
__device__ __forceinline__ int window_reverse_row(int m) {
  int widx = m / 49, pos = m % 49;
  int b = widx >> 2, wh = (widx >> 1) & 1, ww = widx & 1;
  int i = pos / 7, j = pos % 7;
  return b * 196 + (wh * 7 + i) * 14 + (ww * 7 + j);
}

__device__ __forceinline__ void gload16(const void* g, void* l) {
  __builtin_amdgcn_global_load_lds(
      (const __attribute__((address_space(1))) void*)g,
      (__attribute__((address_space(3))) void*)l, 16, 0, 0);
}

// ---------------------------------------------------------------------------
// bf16 MFMA GEMM: A [M][K] bf16, BT [N][K] bf16, 128x128 tile, BK=64.
// Single-buffered m97 2-barrier K-loop, XOR-swizzled LDS, XCD-chunked block
// swizzle + n-fastest tile order. bf16 epilogue: f32 LDS bounce (2 half-tile
// passes) + read-side v_cvt_pk_bf16_f32 (VALU diet vs scalar f2bf).
// EPI 0: Cout(bf16)=acc+bias ; 1: gelu ; 2: f32 RMW window_reverse ;
// 3: f32 RMW rowbase+m ; 4: f32 store
template <int EPI>
__global__ __launch_bounds__(256) void k_gemm_mfma(const unsigned short* __restrict__ A,
                                                   const unsigned short* __restrict__ BT,
                                                   const float* __restrict__ bias,
                                                   void* __restrict__ Cout,
                                                   int rowbase, int N, int K, int nNt) {
  __shared__ __align__(128) unsigned short S[16384];   // 32 KB
  const int t = threadIdx.x;
  const int lane = t & 63, w = t >> 6;
  const int wr = w >> 1, wc = w & 1;
  const int cpx = gridDim.x >> 3;
  const int lb = (blockIdx.x & 7) * cpx + (blockIdx.x >> 3);
  const int n_t = lb % nNt, m_t = lb / nNt;
  const int m0 = m_t * BM, n0 = n_t * BN;
  const int l15 = lane & 15;
  const int sw = (lane & 7) << 3;                 // read-side XOR (elements)
  const int rA = lane >> 3;                       // staging row within segment
  const int kin = (((lane & 7) ^ rA) << 3);       // swizzled source col (elems)
  ffrag4 acc[4][4] = {};

  for (int k0 = 0; k0 < K; k0 += BK) {
#pragma unroll
    for (int i = 0; i < 4; ++i) {
      const int seg = i * 4 + w;                  // wave-uniform 0..15
      const int row = seg * 8 + rA;               // 0..127
      gload16(A + (size_t)(m0 + row) * K + k0 + kin, (char*)S + seg * 1024);
      gload16(BT + (size_t)(n0 + row) * K + k0 + kin, (char*)S + 16384 + seg * 1024);
    }
    __syncthreads();
#pragma unroll
    for (int kk = 0; kk < BK; kk += 32) {
      bfrag8 af[4], bfr[4];
      const int colA = (kk + (lane >> 4) * 8) ^ sw;
#pragma unroll
      for (int mi = 0; mi < 4; ++mi) {
        int row = wr * 64 + mi * 16 + l15;
        af[mi] = *(const bfrag8*)&S[row * BK + colA];
      }
#pragma unroll
      for (int ni = 0; ni < 4; ++ni) {
        int col = wc * 64 + ni * 16 + l15;
        bfr[ni] = *(const bfrag8*)&S[8192 + col * BK + colA];
      }
#pragma unroll
      for (int mi = 0; mi < 4; ++mi)
#pragma unroll
        for (int ni = 0; ni < 4; ++ni)
          acc[mi][ni] = __builtin_amdgcn_mfma_f32_16x16x32_bf16(af[mi], bfr[ni], acc[mi][ni], 0, 0, 0);
    }
    __syncthreads();
  }

  const int cr = (lane >> 4) * 4;
  const int cc = l15;
  float bv[4];
#pragma unroll
  for (int ni = 0; ni < 4; ++ni) bv[ni] = bias[n0 + wc * 64 + ni * 16 + cc];

  if (EPI == 0 || EPI == 1) {
    // f32 bounce, two half-tile passes (rows [pass*64, pass*64+64))
    float* Sf = (float*)S;    // 8192 f32 = 64 rows x 128 cols
#pragma unroll
    for (int pass = 0; pass < 2; ++pass) {
      if (wr == pass) {
#pragma unroll
        for (int mi = 0; mi < 4; ++mi) {
#pragma unroll
          for (int j = 0; j < 4; ++j) {
            const int mloc = mi * 16 + cr + j;    // 0..63
#pragma unroll
            for (int ni = 0; ni < 4; ++ni) {
              const int nl = wc * 64 + ni * 16 + cc;
              float v = acc[mi][ni][j] + bv[ni];
              if (EPI == 1) v = gelu_fast(v);
              Sf[mloc * 128 + nl] = v;
            }
          }
        }
      }
      __syncthreads();
#pragma unroll
      for (int r = 0; r < 4; ++r) {
        const int flat = (r * 256 + t) * 8;       // f32 index, 0..8191
        const int ml = flat >> 7, nl = flat & 127;
        float4 a = *(const float4*)&Sf[flat];
        float4 b2 = *(const float4*)&Sf[flat + 4];
        uint4 o;
        o.x = cvtpk(a.x, a.y);  o.y = cvtpk(a.z, a.w);
        o.z = cvtpk(b2.x, b2.y); o.w = cvtpk(b2.z, b2.w);
        *(uint4*)((unsigned short*)Cout + (size_t)(m0 + pass * 64 + ml) * N + n0 + nl) = o;
      }
      if (pass == 0) __syncthreads();
    }
  } else {
#pragma unroll
    for (int mi = 0; mi < 4; ++mi) {
#pragma unroll
      for (int j = 0; j < 4; ++j) {
        const int m = m0 + wr * 64 + mi * 16 + cr + j;
        int row;
        if (EPI == 2) row = window_reverse_row(rowbase + m);
        else if (EPI == 3) row = rowbase + m;
        else row = m;
#pragma unroll
        for (int ni = 0; ni < 4; ++ni) {
          const int n = n0 + wc * 64 + ni * 16 + cc;
          float v = acc[mi][ni][j] + bv[ni];
          if (EPI == 4) {
            ((float*)Cout)[(size_t)row * N + n] = v;
          } else {
            float* p = (float*)Cout + (size_t)row * N + n;
            *p += v;
          }
        }
      }
    }
  }
}

// ---------------------------------------------------------------------------
__global__ __launch_bounds__(256) void k_wtrans(const float* __restrict__ w,
                                                unsigned short* __restrict__ wt,
                                                int K, int N) {
  __shared__ float tile[32][33];
  int k0 = blockIdx.x * 32, n0 = blockIdx.y * 32;
  int tx = threadIdx.x & 31, ty = threadIdx.x >> 5;
#pragma unroll
  for (int r = 0; r < 4; ++r)
    tile[ty + r * 8][tx] = w[(size_t)(k0 + ty + r * 8) * N + n0 + tx];
  __syncthreads();
#pragma unroll
  for (int r = 0; r < 4; ++r)
    wt[(size_t)(n0 + ty + r * 8) * K + k0 + tx] = f2bf(tile[tx][ty + r * 8]);
}

__global__ __launch_bounds__(256) void k_cast(const float* __restrict__ w,
                                              unsigned short* __restrict__ wb, int n) {
  int i = blockIdx.x * 256 + threadIdx.x;
  if (i < n) wb[i] = f2bf(w[i]);
}

__global__ __launch_bounds__(256) void k_transpose_x(const float* __restrict__ x,
                                                     unsigned short* __restrict__ xt) {
  __shared__ float tile[32][33];
  int b = blockIdx.x;
  int hw0 = blockIdx.y * 32;
  int c0 = blockIdx.z * 32;
  int tx = threadIdx.x & 31, ty = threadIdx.x >> 5;
#pragma unroll
  for (int r = 0; r < 4; ++r) {
    int c = c0 + ty + r * 8, hw = hw0 + tx;
    if (hw < HWTOK) tile[ty + r * 8][tx] = x[((size_t)b * 256 + c) * HWTOK + hw];
  }
  __syncthreads();
#pragma unroll
  for (int r = 0; r < 4; ++r) {
    int hw = hw0 + ty + r * 8, c = c0 + tx;
    if (hw < HWTOK) xt[((size_t)b * HWTOK + hw) * 256 + c] = f2bf(tile[tx][ty + r * 8]);
  }
}

// ---------------------------------------------------------------------------
template <bool WINDOW>
__global__ __launch_bounds__(256) void k_layernorm(const float* __restrict__ in,
                                                   const float* __restrict__ g,
                                                   const float* __restrict__ bta,
                                                   unsigned short* __restrict__ out,
                                                   int rowbase) {
  int wid = threadIdx.x >> 6, lane = threadIdx.x & 63;
  int li = blockIdx.x * 4 + wid;
  int token = rowbase + li;
  const float4 xv = *(const float4*)(in + (size_t)token * 256 + lane * 4);
  float s = xv.x + xv.y + xv.z + xv.w;
  float sq = xv.x * xv.x + xv.y * xv.y + xv.z * xv.z + xv.w * xv.w;
#pragma unroll
  for (int off = 32; off >= 1; off >>= 1) {
    s += __shfl_xor(s, off);
    sq += __shfl_xor(sq, off);
  }
  float mean = s * (1.f / 256.f);
  float var = sq * (1.f / 256.f) - mean * mean;
  float rstd = rsqrtf(var + 1e-5f);
  float4 gv = *(const float4*)(g + lane * 4);
  float4 bv = *(const float4*)(bta + lane * 4);
  uint2 ov;
  ov.x = cvtpk((xv.x - mean) * rstd * gv.x + bv.x,
               (xv.y - mean) * rstd * gv.y + bv.y);
  ov.y = cvtpk((xv.z - mean) * rstd * gv.z + bv.z,
               (xv.w - mean) * rstd * gv.w + bv.w);
  int orow;
  if (WINDOW) {
    int b = token / 196, hw = token % 196;
    int h14 = hw / 14, w14 = hw % 14;
    int wh = h14 / 7, i = h14 % 7, ww = w14 / 7, j = w14 % 7;
    int widx = (b * 2 + wh) * 2 + ww;
    orow = widx * 49 + i * 7 + j - rowbase;
  } else {
    orow = li;
  }
  *(uint2*)(out + (size_t)orow * 256 + lane * 4) = ov;
}

// ---------------------------------------------------------------------------
// MFMA attention: one WAVE per (window, head); 4 independent waves per block.
__global__ __launch_bounds__(256) void k_attention(const unsigned short* __restrict__ qkv,
                                                   const float* __restrict__ rpb,
                                                   unsigned short* __restrict__ o) {
  __shared__ unsigned short Kl[4][64 * 40];
  __shared__ unsigned short VTl[4][32 * 72];
  __shared__ unsigned short Pl[4][64 * 72];
  __shared__ float rpbl[4][176];

  const int t = threadIdx.x;
  const int w4 = t >> 6, lane = t & 63;
  const int l15 = lane & 15, g = lane >> 4;
  const int gw = blockIdx.x * 4 + w4;
  const int lw = gw >> 3, head = gw & 7;

  unsigned short* K_ = Kl[w4];
  unsigned short* VT_ = VTl[w4];
  unsigned short* P_ = Pl[w4];
  float* rpb_ = rpbl[w4];

  const size_t baseq = (size_t)lw * 49 * 768 + head * 32;

  for (int e = lane; e < 169; e += 64) rpb_[e] = rpb[e * 8 + head];

  for (int e = lane; e < 512; e += 64) {
    int d = e >> 4, tk = 48 + (e & 15);
    if ((e & 15) != 0) VT_[d * 72 + tk] = 0;
  }

  for (int e = lane; e < 784; e += 64) {
    int tok = e >> 4, dp = e & 15;
    unsigned kv = *(const unsigned*)(qkv + baseq + 256 + (size_t)tok * 768 + dp * 2);
    *(unsigned*)&K_[tok * 40 + dp * 2] = kv;
    unsigned vv = *(const unsigned*)(qkv + baseq + 512 + (size_t)tok * 768 + dp * 2);
    VT_[(dp * 2 + 0) * 72 + tok] = (unsigned short)(vv & 0xffffu);
    VT_[(dp * 2 + 1) * 72 + tok] = (unsigned short)(vv >> 16);
  }

  ffrag4 acc[4][4] = {};
  {
    bfrag8 af[4], bfr[4];
#pragma unroll
    for (int qi = 0; qi < 4; ++qi)
      af[qi] = *(const bfrag8*)(qkv + baseq + (size_t)(16 * qi + l15) * 768 + g * 8);
#pragma unroll
    for (int kj = 0; kj < 4; ++kj)
      bfr[kj] = *(const bfrag8*)&K_[(16 * kj + l15) * 40 + g * 8];
#pragma unroll
    for (int qi = 0; qi < 4; ++qi)
#pragma unroll
      for (int kj = 0; kj < 4; ++kj)
        acc[qi][kj] = __builtin_amdgcn_mfma_f32_16x16x32_bf16(af[qi], bfr[kj], acc[qi][kj], 0, 0, 0);
  }

  const float scale = 0.17677669529663687f;
  int kc[4];
  bool kvalid[4];
#pragma unroll
  for (int kj = 0; kj < 4; ++kj) {
    int c = 16 * kj + l15;
    kc[kj] = 13 * (c / 7) + (c % 7);
    kvalid[kj] = (c < 49);
  }
#pragma unroll
  for (int qi = 0; qi < 4; ++qi) {
#pragma unroll
    for (int j = 0; j < 4; ++j) {
      int q = 16 * qi + 4 * g + j;
      int qc = 13 * (q / 7) + (q % 7);
      float tv[4];
#pragma unroll
      for (int kj = 0; kj < 4; ++kj)
        tv[kj] = kvalid[kj] ? (acc[qi][kj][j] * scale + rpb_[qc - kc[kj] + 84]) : -INFINITY;
      float mx = fmaxf(fmaxf(tv[0], tv[1]), fmaxf(tv[2], tv[3]));
#pragma unroll
      for (int off = 8; off >= 1; off >>= 1) mx = fmaxf(mx, __shfl_xor(mx, off));
      float p[4], sum = 0.f;
#pragma unroll
      for (int kj = 0; kj < 4; ++kj) {
        p[kj] = kvalid[kj] ? __expf(tv[kj] - mx) : 0.f;
        sum += p[kj];
      }
#pragma unroll
      for (int off = 8; off >= 1; off >>= 1) sum += __shfl_xor(sum, off);
      float inv = __builtin_amdgcn_rcpf(sum);
      if (q < 49) {
#pragma unroll
        for (int kj = 0; kj < 4; ++kj)
          P_[q * 72 + 16 * kj + l15] = f2bf(p[kj] * inv);
      }
    }
  }

  ffrag4 accO[2][4] = {};
#pragma unroll
  for (int kk = 0; kk < 64; kk += 32) {
    bfrag8 af2[2], bf2[4];
#pragma unroll
    for (int ti = 0; ti < 2; ++ti)
      af2[ti] = *(const bfrag8*)&VT_[(16 * ti + l15) * 72 + kk + g * 8];
#pragma unroll
    for (int qj = 0; qj < 4; ++qj)
      bf2[qj] = *(const bfrag8*)&P_[(16 * qj + l15) * 72 + kk + g * 8];
#pragma unroll
    for (int ti = 0; ti < 2; ++ti)
#pragma unroll
      for (int qj = 0; qj < 4; ++qj)
        accO[ti][qj] = __builtin_amdgcn_mfma_f32_16x16x32_bf16(af2[ti], bf2[qj], accO[ti][qj], 0, 0, 0);
  }

#pragma unroll
  for (int qj = 0; qj < 4; ++qj) {
    int q = 16 * qj + l15;
    if (q < 49) {
#pragma unroll
      for (int ti = 0; ti < 2; ++ti) {
        uint2 ov;
        ov.x = cvtpk(accO[ti][qj][0], accO[ti][qj][1]);
        ov.y = cvtpk(accO[ti][qj][2], accO[ti][qj][3]);
        *(uint2*)(o + ((size_t)lw * 49 + q) * 256 + head * 32 + 16 * ti + 4 * g) = ov;
      }
    }
  }
}

// ---------------------------------------------------------------------------
__global__ __launch_bounds__(256) void k_pool(const float* __restrict__ tok,
                                              float* __restrict__ pooled) {
  int b = blockIdx.x, c = threadIdx.x;
  float s = 0.f;
  for (int hw = 0; hw < 196; ++hw) s += tok[((size_t)b * 196 + hw) * 256 + c];
  pooled[b * 256 + c] = s * (1.f / 196.f);
}

__global__ __launch_bounds__(64) void k_head(const float* __restrict__ pooled,
                                             const float* __restrict__ w,
                                             const float* __restrict__ bias,
                                             float* __restrict__ out) {
  int b = blockIdx.x, t = threadIdx.x;
  if (t < 7) {
    float s = bias[t];
    for (int c = 0; c < 256; ++c) s = fmaf(pooled[b * 256 + c], w[c * 7 + t], s);
    out[b * 7 + t] = s;
  }
}

// ---------------------------------------------------------------------------
extern "C" void kernel_launch(void* const* d_in, const int* in_sizes, int n_in,
                              void* d_out, int out_size, void* d_ws, size_t ws_size,
                              hipStream_t stream) {
  const float* x      = (const float*)d_in[0];
  const float* conv_w = (const float*)d_in[1];
  const float* conv_b = (const float*)d_in[2];
  const float* ln1_g  = (const float*)d_in[3];
  const float* ln1_b  = (const float*)d_in[4];
  const float* qkv_w  = (const float*)d_in[5];
  const float* qkv_b  = (const float*)d_in[6];
  const float* rpb    = (const float*)d_in[7];
  const float* proj_w = (const float*)d_in[8];
  const float* proj_b = (const float*)d_in[9];
  const float* ln2_g  = (const float*)d_in[10];
  const float* ln2_b  = (const float*)d_in[11];
  const float* fc1_w  = (const float*)d_in[12];
  const float* fc1_b  = (const float*)d_in[13];
  const float* fc2_w  = (const float*)d_in[14];
  const float* fc2_b  = (const float*)d_in[15];
  const float* fco_w  = (const float*)d_in[16];
  const float* fco_b  = (const float*)d_in[17];
  float* out = (float*)d_out;
  char* p = (char*)d_ws;

  const size_t FULL_NEED = 207486976ull;
  const int nch = (ws_size >= FULL_NEED) ? 1 : 4;
  const int chw = 1024 / nch;
  const size_t chrows = (size_t)chw * 49;
  const int nMt = (int)(chrows / BM);

  float* tok = (float*)p;                     p += (size_t)MTOT * 256 * 4;
  unsigned short* Bbuf = (unsigned short*)p;  p += chrows * 1024 * 2;
  unsigned short* Abuf = (unsigned short*)p;  p += chrows * 256 * 2;
  unsigned short* Cbuf = (unsigned short*)p;  p += chrows * 256 * 2;
  unsigned short* cwB  = (unsigned short*)p;  p += 65536 * 2;
  unsigned short* qkvT = (unsigned short*)p;  p += 196608 * 2;
  unsigned short* projT= (unsigned short*)p;  p += 65536 * 2;
  unsigned short* fc1T = (unsigned short*)p;  p += 262144 * 2;
  unsigned short* fc2T = (unsigned short*)p;  p += 262144 * 2;
  float* pool = (float*)p;                    p += 65536 * 4;
  unsigned short* xt = Bbuf;

  k_cast<<<256, 256, 0, stream>>>(conv_w, cwB, 65536);
  k_wtrans<<<dim3(8, 24), 256, 0, stream>>>(qkv_w, qkvT, 256, 768);
  k_wtrans<<<dim3(8, 8), 256, 0, stream>>>(proj_w, projT, 256, 256);
  k_wtrans<<<dim3(8, 32), 256, 0, stream>>>(fc1_w, fc1T, 256, 1024);
  k_wtrans<<<dim3(32, 8), 256, 0, stream>>>(fc2_w, fc2T, 1024, 256);

  k_transpose_x<<<dim3(BATCH, 7, 8), 256, 0, stream>>>(x, xt);
  k_gemm_mfma<4><<<(MTOT / BM) * 2, 256, 0, stream>>>(xt, cwB, conv_b, tok, 0, 256, 256, 2);

  for (int c = 0; c < nch; ++c) {
    const int rowbase = c * (int)chrows;
    k_layernorm<true><<<chrows / 4, 256, 0, stream>>>(tok, ln1_g, ln1_b, Abuf, rowbase);
    k_gemm_mfma<0><<<nMt * 6, 256, 0, stream>>>(Abuf, qkvT, qkv_b, Bbuf, 0, 768, 256, 6);
    k_attention<<<chw * 2, 256, 0, stream>>>(Bbuf, rpb, Cbuf);
    k_gemm_mfma<2><<<nMt * 2, 256, 0, stream>>>(Cbuf, projT, proj_b, tok, rowbase, 256, 256, 2);
    k_layernorm<false><<<chrows / 4, 256, 0, stream>>>(tok, ln2_g, ln2_b, Abuf, rowbase);
    k_gemm_mfma<1><<<nMt * 8, 256, 0, stream>>>(Abuf, fc1T, fc1_b, Bbuf, 0, 1024, 256, 8);
    k_gemm_mfma<3><<<nMt * 2, 256, 0, stream>>>(Bbuf, fc2T, fc2_b, tok, rowbase, 256, 1024, 2);
  }

  k_pool<<<BATCH, 256, 0, stream>>>(tok, pool);
  k_head<<<BATCH, 64, 0, stream>>>(pool, fco_w, fco_b, out);
}

// Round 12
// 307.149 us; speedup vs baseline: 5.9953x; 1.0814x over previous
//
#include <hip/hip_runtime.h>
#include <math.h>

#define NHEADS 8
#define BATCH  256
#define HWTOK  196
#define MTOT   50176          // 1024 windows * 49

#define BM 128
#define BN 128
#define BK 64

typedef short bfrag8 __attribute__((ext_vector_type(8)));
typedef float ffrag4 __attribute__((ext_vector_type(4)));

// ---------------------------------------------------------------------------
__device__ __forceinline__ unsigned short f2bf(float f) {
  union { float f; unsigned u; } v; v.f = f;
  unsigned r = v.u + 0x7fffu + ((v.u >> 16) & 1u);   // RNE
  return (unsigned short)(r >> 16);
}
__device__ __forceinline__ float bf2f(unsigned short b) {
  union { unsigned u; float f; } v; v.u = ((unsigned)b) << 16;
  return v.f;
}
__device__ __forceinline__ float bflo(unsigned u) {
  union { unsigned x; float f; } v; v.x = u << 16; return v.f;
}
__device__ __forceinline__ float bfhi(unsigned u) {
  union { unsigned x; float f; } v; v.x = u & 0xffff0000u; return v.f;
}
// packed bf16 convert: lo = bf16(a), hi = bf16(b), RNE
__device__ __forceinline__ unsigned cvtpk(float a, float b) {
  unsigned r;
  asm("v_cvt_pk_bf16_f32 %0, %1, %2" : "=v"(r) : "v"(a), "v"(b));
  return r;
}
// GELU exact-erf (A&S 7.1.26, |err|<=1.5e-7) with fast rcp
__device__ __forceinline__ float gelu_fast(float x) {
  float ax = fabsf(x);
  float z = ax * 0.70710678118654752f;
  float t = __builtin_amdgcn_rcpf(fmaf(z, 0.3275911f, 1.0f));
  float y = t * (0.254829592f +
            t * (-0.284496736f +
            t * (1.421413741f +
            t * (-1.453152027f +
            t * 1.061405429f))));
  float e2 = __expf(-z * z);
  float erfv = fmaf(-y, e2, 1.0f);
  return 0.5f * fmaf(ax, erfv, x);
}
__device__ __forceinline__ int window_reverse_row(int m) {
  int widx = m / 49, pos = m % 49;
  int b = widx >> 2, wh = (widx >> 1) & 1, ww = widx & 1;
  int i = pos / 7, j = pos % 7;
  return b * 196 + (wh * 7 + i) * 14 + (ww * 7 + j);
}

__device__ __forceinline__ void gload16(const void* g, void* l) {
  __builtin_amdgcn_global_load_lds(
      (const __attribute__((address_space(1))) void*)g,
      (__attribute__((address_space(3))) void*)l, 16, 0, 0);
}

// ---------------------------------------------------------------------------
// bf16 MFMA GEMM: A [M][K] bf16, BT [N][K] bf16, 128x128 tile, BK=64.
// Single-buffered m97 2-barrier K-loop, XOR-swizzled LDS, XCD-chunked block
// swizzle + n-fastest tile order, f32-LDS-bounce epilogues + cvt_pk packing.
// EPI 0: Cout(bf16)[m] = acc+bias
// EPI 1: Cout(bf16)[m] = gelu(acc+bias)
// EPI 2: Cout(bf16)[wrr(rowbase+m)] += acc+bias   (residual RMW, bf16)
// EPI 3: Cout(bf16)[rowbase+m]      += acc+bias   (residual RMW, bf16)
template <int EPI>
__global__ __launch_bounds__(256) void k_gemm_mfma(const unsigned short* __restrict__ A,
                                                   const unsigned short* __restrict__ BT,
                                                   const float* __restrict__ bias,
                                                   void* __restrict__ Cout,
                                                   int rowbase, int N, int K, int nNt) {
  __shared__ __align__(128) unsigned short S[16384];   // 32 KB
  const int t = threadIdx.x;
  const int lane = t & 63, w = t >> 6;
  const int wr = w >> 1, wc = w & 1;
  const int cpx = gridDim.x >> 3;
  const int lb = (blockIdx.x & 7) * cpx + (blockIdx.x >> 3);
  const int n_t = lb % nNt, m_t = lb / nNt;
  const int m0 = m_t * BM, n0 = n_t * BN;
  const int l15 = lane & 15;
  const int sw = (lane & 7) << 3;                 // read-side XOR (elements)
  const int rA = lane >> 3;                       // staging row within segment
  const int kin = (((lane & 7) ^ rA) << 3);       // swizzled source col (elems)
  ffrag4 acc[4][4] = {};

  for (int k0 = 0; k0 < K; k0 += BK) {
#pragma unroll
    for (int i = 0; i < 4; ++i) {
      const int seg = i * 4 + w;                  // wave-uniform 0..15
      const int row = seg * 8 + rA;               // 0..127
      gload16(A + (size_t)(m0 + row) * K + k0 + kin, (char*)S + seg * 1024);
      gload16(BT + (size_t)(n0 + row) * K + k0 + kin, (char*)S + 16384 + seg * 1024);
    }
    __syncthreads();
#pragma unroll
    for (int kk = 0; kk < BK; kk += 32) {
      bfrag8 af[4], bfr[4];
      const int colA = (kk + (lane >> 4) * 8) ^ sw;
#pragma unroll
      for (int mi = 0; mi < 4; ++mi) {
        int row = wr * 64 + mi * 16 + l15;
        af[mi] = *(const bfrag8*)&S[row * BK + colA];
      }
#pragma unroll
      for (int ni = 0; ni < 4; ++ni) {
        int col = wc * 64 + ni * 16 + l15;
        bfr[ni] = *(const bfrag8*)&S[8192 + col * BK + colA];
      }
#pragma unroll
      for (int mi = 0; mi < 4; ++mi)
#pragma unroll
        for (int ni = 0; ni < 4; ++ni)
          acc[mi][ni] = __builtin_amdgcn_mfma_f32_16x16x32_bf16(af[mi], bfr[ni], acc[mi][ni], 0, 0, 0);
    }
    __syncthreads();
  }

  const int cr = (lane >> 4) * 4;
  const int cc = l15;
  float bv[4];
#pragma unroll
  for (int ni = 0; ni < 4; ++ni) bv[ni] = bias[n0 + wc * 64 + ni * 16 + cc];

  // f32 bounce, two half-tile passes (rows [pass*64, pass*64+64))
  float* Sf = (float*)S;    // 8192 f32 = 64 rows x 128 cols
#pragma unroll
  for (int pass = 0; pass < 2; ++pass) {
    if (wr == pass) {
#pragma unroll
      for (int mi = 0; mi < 4; ++mi) {
#pragma unroll
        for (int j = 0; j < 4; ++j) {
          const int mloc = mi * 16 + cr + j;      // 0..63
#pragma unroll
          for (int ni = 0; ni < 4; ++ni) {
            const int nl = wc * 64 + ni * 16 + cc;
            float v = acc[mi][ni][j] + bv[ni];
            if (EPI == 1) v = gelu_fast(v);
            Sf[mloc * 128 + nl] = v;
          }
        }
      }
    }
    __syncthreads();
#pragma unroll
    for (int r = 0; r < 4; ++r) {
      const int flat = (r * 256 + t) * 8;         // f32 index, 0..8191
      const int ml = flat >> 7, nl = flat & 127;
      float4 a = *(const float4*)&Sf[flat];
      float4 b2 = *(const float4*)&Sf[flat + 4];
      uint4 o;
      if (EPI == 2 || EPI == 3) {
        const int gm = rowbase + m0 + pass * 64 + ml;
        const int row = (EPI == 2) ? window_reverse_row(gm) : gm;
        unsigned short* dst = (unsigned short*)Cout + (size_t)row * N + n0 + nl;
        uint4 old = *(const uint4*)dst;
        o.x = cvtpk(bflo(old.x) + a.x, bfhi(old.x) + a.y);
        o.y = cvtpk(bflo(old.y) + a.z, bfhi(old.y) + a.w);
        o.z = cvtpk(bflo(old.z) + b2.x, bfhi(old.z) + b2.y);
        o.w = cvtpk(bflo(old.w) + b2.z, bfhi(old.w) + b2.w);
        *(uint4*)dst = o;
      } else {
        o.x = cvtpk(a.x, a.y);  o.y = cvtpk(a.z, a.w);
        o.z = cvtpk(b2.x, b2.y); o.w = cvtpk(b2.z, b2.w);
        *(uint4*)((unsigned short*)Cout + (size_t)(m0 + pass * 64 + ml) * N + n0 + nl) = o;
      }
    }
    if (pass == 0) __syncthreads();
  }
}

// ---------------------------------------------------------------------------
__global__ __launch_bounds__(256) void k_wtrans(const float* __restrict__ w,
                                                unsigned short* __restrict__ wt,
                                                int K, int N) {
  __shared__ float tile[32][33];
  int k0 = blockIdx.x * 32, n0 = blockIdx.y * 32;
  int tx = threadIdx.x & 31, ty = threadIdx.x >> 5;
#pragma unroll
  for (int r = 0; r < 4; ++r)
    tile[ty + r * 8][tx] = w[(size_t)(k0 + ty + r * 8) * N + n0 + tx];
  __syncthreads();
#pragma unroll
  for (int r = 0; r < 4; ++r)
    wt[(size_t)(n0 + ty + r * 8) * K + k0 + tx] = f2bf(tile[tx][ty + r * 8]);
}

__global__ __launch_bounds__(256) void k_cast(const float* __restrict__ w,
                                              unsigned short* __restrict__ wb, int n) {
  int i = blockIdx.x * 256 + threadIdx.x;
  if (i < n) wb[i] = f2bf(w[i]);
}

__global__ __launch_bounds__(256) void k_transpose_x(const float* __restrict__ x,
                                                     unsigned short* __restrict__ xt) {
  __shared__ float tile[32][33];
  int b = blockIdx.x;
  int hw0 = blockIdx.y * 32;
  int c0 = blockIdx.z * 32;
  int tx = threadIdx.x & 31, ty = threadIdx.x >> 5;
#pragma unroll
  for (int r = 0; r < 4; ++r) {
    int c = c0 + ty + r * 8, hw = hw0 + tx;
    if (hw < HWTOK) tile[ty + r * 8][tx] = x[((size_t)b * 256 + c) * HWTOK + hw];
  }
  __syncthreads();
#pragma unroll
  for (int r = 0; r < 4; ++r) {
    int hw = hw0 + ty + r * 8, c = c0 + tx;
    if (hw < HWTOK) xt[((size_t)b * HWTOK + hw) * 256 + c] = f2bf(tile[tx][ty + r * 8]);
  }
}

// ---------------------------------------------------------------------------
// LayerNorm over C=256, one wave/token, bf16 in -> bf16 out (chunk-local rows).
template <bool WINDOW>
__global__ __launch_bounds__(256) void k_layernorm(const unsigned short* __restrict__ in,
                                                   const float* __restrict__ g,
                                                   const float* __restrict__ bta,
                                                   unsigned short* __restrict__ out,
                                                   int rowbase) {
  int wid = threadIdx.x >> 6, lane = threadIdx.x & 63;
  int li = blockIdx.x * 4 + wid;
  int token = rowbase + li;
  const uint2 xr = *(const uint2*)(in + (size_t)token * 256 + lane * 4);
  float x0 = bflo(xr.x), x1 = bfhi(xr.x), x2 = bflo(xr.y), x3 = bfhi(xr.y);
  float s = x0 + x1 + x2 + x3;
  float sq = x0 * x0 + x1 * x1 + x2 * x2 + x3 * x3;
#pragma unroll
  for (int off = 32; off >= 1; off >>= 1) {
    s += __shfl_xor(s, off);
    sq += __shfl_xor(sq, off);
  }
  float mean = s * (1.f / 256.f);
  float var = sq * (1.f / 256.f) - mean * mean;
  float rstd = rsqrtf(var + 1e-5f);
  float4 gv = *(const float4*)(g + lane * 4);
  float4 bv = *(const float4*)(bta + lane * 4);
  uint2 ov;
  ov.x = cvtpk((x0 - mean) * rstd * gv.x + bv.x,
               (x1 - mean) * rstd * gv.y + bv.y);
  ov.y = cvtpk((x2 - mean) * rstd * gv.z + bv.z,
               (x3 - mean) * rstd * gv.w + bv.w);
  int orow;
  if (WINDOW) {
    int b = token / 196, hw = token % 196;
    int h14 = hw / 14, w14 = hw % 14;
    int wh = h14 / 7, i = h14 % 7, ww = w14 / 7, j = w14 % 7;
    int widx = (b * 2 + wh) * 2 + ww;
    orow = widx * 49 + i * 7 + j - rowbase;
  } else {
    orow = li;
  }
  *(uint2*)(out + (size_t)orow * 256 + lane * 4) = ov;
}

// ---------------------------------------------------------------------------
// MFMA attention: one WAVE per (window, head); 4 independent waves per block.
__global__ __launch_bounds__(256) void k_attention(const unsigned short* __restrict__ qkv,
                                                   const float* __restrict__ rpb,
                                                   unsigned short* __restrict__ o) {
  __shared__ unsigned short Kl[4][64 * 40];
  __shared__ unsigned short VTl[4][32 * 72];
  __shared__ unsigned short Pl[4][64 * 72];
  __shared__ float rpbl[4][176];

  const int t = threadIdx.x;
  const int w4 = t >> 6, lane = t & 63;
  const int l15 = lane & 15, g = lane >> 4;
  const int gw = blockIdx.x * 4 + w4;
  const int lw = gw >> 3, head = gw & 7;

  unsigned short* K_ = Kl[w4];
  unsigned short* VT_ = VTl[w4];
  unsigned short* P_ = Pl[w4];
  float* rpb_ = rpbl[w4];

  const size_t baseq = (size_t)lw * 49 * 768 + head * 32;

  for (int e = lane; e < 169; e += 64) rpb_[e] = rpb[e * 8 + head];

  for (int e = lane; e < 512; e += 64) {
    int d = e >> 4, tk = 48 + (e & 15);
    if ((e & 15) != 0) VT_[d * 72 + tk] = 0;
  }

  for (int e = lane; e < 784; e += 64) {
    int tok = e >> 4, dp = e & 15;
    unsigned kv = *(const unsigned*)(qkv + baseq + 256 + (size_t)tok * 768 + dp * 2);
    *(unsigned*)&K_[tok * 40 + dp * 2] = kv;
    unsigned vv = *(const unsigned*)(qkv + baseq + 512 + (size_t)tok * 768 + dp * 2);
    VT_[(dp * 2 + 0) * 72 + tok] = (unsigned short)(vv & 0xffffu);
    VT_[(dp * 2 + 1) * 72 + tok] = (unsigned short)(vv >> 16);
  }

  ffrag4 acc[4][4] = {};
  {
    bfrag8 af[4], bfr[4];
#pragma unroll
    for (int qi = 0; qi < 4; ++qi)
      af[qi] = *(const bfrag8*)(qkv + baseq + (size_t)(16 * qi + l15) * 768 + g * 8);
#pragma unroll
    for (int kj = 0; kj < 4; ++kj)
      bfr[kj] = *(const bfrag8*)&K_[(16 * kj + l15) * 40 + g * 8];
#pragma unroll
    for (int qi = 0; qi < 4; ++qi)
#pragma unroll
      for (int kj = 0; kj < 4; ++kj)
        acc[qi][kj] = __builtin_amdgcn_mfma_f32_16x16x32_bf16(af[qi], bfr[kj], acc[qi][kj], 0, 0, 0);
  }

  const float scale = 0.17677669529663687f;
  int kc[4];
  bool kvalid[4];
#pragma unroll
  for (int kj = 0; kj < 4; ++kj) {
    int c = 16 * kj + l15;
    kc[kj] = 13 * (c / 7) + (c % 7);
    kvalid[kj] = (c < 49);
  }
#pragma unroll
  for (int qi = 0; qi < 4; ++qi) {
#pragma unroll
    for (int j = 0; j < 4; ++j) {
      int q = 16 * qi + 4 * g + j;
      int qc = 13 * (q / 7) + (q % 7);
      float tv[4];
#pragma unroll
      for (int kj = 0; kj < 4; ++kj)
        tv[kj] = kvalid[kj] ? (acc[qi][kj][j] * scale + rpb_[qc - kc[kj] + 84]) : -INFINITY;
      float mx = fmaxf(fmaxf(tv[0], tv[1]), fmaxf(tv[2], tv[3]));
#pragma unroll
      for (int off = 8; off >= 1; off >>= 1) mx = fmaxf(mx, __shfl_xor(mx, off));
      float p[4], sum = 0.f;
#pragma unroll
      for (int kj = 0; kj < 4; ++kj) {
        p[kj] = kvalid[kj] ? __expf(tv[kj] - mx) : 0.f;
        sum += p[kj];
      }
#pragma unroll
      for (int off = 8; off >= 1; off >>= 1) sum += __shfl_xor(sum, off);
      float inv = __builtin_amdgcn_rcpf(sum);
      if (q < 49) {
#pragma unroll
        for (int kj = 0; kj < 4; ++kj)
          P_[q * 72 + 16 * kj + l15] = f2bf(p[kj] * inv);
      }
    }
  }

  ffrag4 accO[2][4] = {};
#pragma unroll
  for (int kk = 0; kk < 64; kk += 32) {
    bfrag8 af2[2], bf2[4];
#pragma unroll
    for (int ti = 0; ti < 2; ++ti)
      af2[ti] = *(const bfrag8*)&VT_[(16 * ti + l15) * 72 + kk + g * 8];
#pragma unroll
    for (int qj = 0; qj < 4; ++qj)
      bf2[qj] = *(const bfrag8*)&P_[(16 * qj + l15) * 72 + kk + g * 8];
#pragma unroll
    for (int ti = 0; ti < 2; ++ti)
#pragma unroll
      for (int qj = 0; qj < 4; ++qj)
        accO[ti][qj] = __builtin_amdgcn_mfma_f32_16x16x32_bf16(af2[ti], bf2[qj], accO[ti][qj], 0, 0, 0);
  }

#pragma unroll
  for (int qj = 0; qj < 4; ++qj) {
    int q = 16 * qj + l15;
    if (q < 49) {
#pragma unroll
      for (int ti = 0; ti < 2; ++ti) {
        uint2 ov;
        ov.x = cvtpk(accO[ti][qj][0], accO[ti][qj][1]);
        ov.y = cvtpk(accO[ti][qj][2], accO[ti][qj][3]);
        *(uint2*)(o + ((size_t)lw * 49 + q) * 256 + head * 32 + 16 * ti + 4 * g) = ov;
      }
    }
  }
}

// ---------------------------------------------------------------------------
__global__ __launch_bounds__(256) void k_pool(const unsigned short* __restrict__ tok,
                                              float* __restrict__ pooled) {
  int b = blockIdx.x, c = threadIdx.x;
  float s = 0.f;
  for (int hw = 0; hw < 196; ++hw) s += bf2f(tok[((size_t)b * 196 + hw) * 256 + c]);
  pooled[b * 256 + c] = s * (1.f / 196.f);
}

__global__ __launch_bounds__(64) void k_head(const float* __restrict__ pooled,
                                             const float* __restrict__ w,
                                             const float* __restrict__ bias,
                                             float* __restrict__ out) {
  int b = blockIdx.x, t = threadIdx.x;
  if (t < 7) {
    float s = bias[t];
    for (int c = 0; c < 256; ++c) s = fmaf(pooled[b * 256 + c], w[c * 7 + t], s);
    out[b * 7 + t] = s;
  }
}

// ---------------------------------------------------------------------------
extern "C" void kernel_launch(void* const* d_in, const int* in_sizes, int n_in,
                              void* d_out, int out_size, void* d_ws, size_t ws_size,
                              hipStream_t stream) {
  const float* x      = (const float*)d_in[0];
  const float* conv_w = (const float*)d_in[1];
  const float* conv_b = (const float*)d_in[2];
  const float* ln1_g  = (const float*)d_in[3];
  const float* ln1_b  = (const float*)d_in[4];
  const float* qkv_w  = (const float*)d_in[5];
  const float* qkv_b  = (const float*)d_in[6];
  const float* rpb    = (const float*)d_in[7];
  const float* proj_w = (const float*)d_in[8];
  const float* proj_b = (const float*)d_in[9];
  const float* ln2_g  = (const float*)d_in[10];
  const float* ln2_b  = (const float*)d_in[11];
  const float* fc1_w  = (const float*)d_in[12];
  const float* fc1_b  = (const float*)d_in[13];
  const float* fc2_w  = (const float*)d_in[14];
  const float* fc2_b  = (const float*)d_in[15];
  const float* fco_w  = (const float*)d_in[16];
  const float* fco_b  = (const float*)d_in[17];
  float* out = (float*)d_out;
  char* p = (char*)d_ws;

  // bf16 tok: full-M needs ~182 MB; chunked (4 chunks) ~66 MB fallback.
  const size_t FULL_NEED = 182000000ull;
  const int nch = (ws_size >= FULL_NEED) ? 1 : 4;
  const int chw = 1024 / nch;
  const size_t chrows = (size_t)chw * 49;
  const int nMt = (int)(chrows / BM);

  unsigned short* tok = (unsigned short*)p;   p += (size_t)MTOT * 256 * 2;
  unsigned short* Bbuf = (unsigned short*)p;  p += chrows * 1024 * 2;
  unsigned short* Abuf = (unsigned short*)p;  p += chrows * 256 * 2;
  unsigned short* Cbuf = (unsigned short*)p;  p += chrows * 256 * 2;
  unsigned short* cwB  = (unsigned short*)p;  p += 65536 * 2;
  unsigned short* qkvT = (unsigned short*)p;  p += 196608 * 2;
  unsigned short* projT= (unsigned short*)p;  p += 65536 * 2;
  unsigned short* fc1T = (unsigned short*)p;  p += 262144 * 2;
  unsigned short* fc2T = (unsigned short*)p;  p += 262144 * 2;
  float* pool = (float*)p;                    p += 65536 * 4;
  unsigned short* xt = Bbuf;

  k_cast<<<256, 256, 0, stream>>>(conv_w, cwB, 65536);
  k_wtrans<<<dim3(8, 24), 256, 0, stream>>>(qkv_w, qkvT, 256, 768);
  k_wtrans<<<dim3(8, 8), 256, 0, stream>>>(proj_w, projT, 256, 256);
  k_wtrans<<<dim3(8, 32), 256, 0, stream>>>(fc1_w, fc1T, 256, 1024);
  k_wtrans<<<dim3(32, 8), 256, 0, stream>>>(fc2_w, fc2T, 1024, 256);

  k_transpose_x<<<dim3(BATCH, 7, 8), 256, 0, stream>>>(x, xt);
  // conv -> tok (bf16, token-major)
  k_gemm_mfma<0><<<(MTOT / BM) * 2, 256, 0, stream>>>(xt, cwB, conv_b, tok, 0, 256, 256, 2);

  for (int c = 0; c < nch; ++c) {
    const int rowbase = c * (int)chrows;
    k_layernorm<true><<<chrows / 4, 256, 0, stream>>>(tok, ln1_g, ln1_b, Abuf, rowbase);
    k_gemm_mfma<0><<<nMt * 6, 256, 0, stream>>>(Abuf, qkvT, qkv_b, Bbuf, 0, 768, 256, 6);
    k_attention<<<chw * 2, 256, 0, stream>>>(Bbuf, rpb, Cbuf);
    k_gemm_mfma<2><<<nMt * 2, 256, 0, stream>>>(Cbuf, projT, proj_b, tok, rowbase, 256, 256, 2);
    k_layernorm<false><<<chrows / 4, 256, 0, stream>>>(tok, ln2_g, ln2_b, Abuf, rowbase);
    k_gemm_mfma<1><<<nMt * 8, 256, 0, stream>>>(Abuf, fc1T, fc1_b, Bbuf, 0, 1024, 256, 8);
    k_gemm_mfma<3><<<nMt * 2, 256, 0, stream>>>(Bbuf, fc2T, fc2_b, tok, rowbase, 256, 1024, 2);
  }

  k_pool<<<BATCH, 256, 0, stream>>>(tok, pool);
  k_head<<<BATCH, 64, 0, stream>>>(pool, fco_w, fco_b, out);
}